// Round 2
// baseline (1696.845 us; speedup 1.0000x reference)
//
#include <hip/hip_runtime.h>
#include <hip/hip_fp16.h>

#define T_ 2048
#define C_ 2048
#define H_ 128
#define E_ 16
#define N_TOK 8192
#define SCALE_ 0.08838834764831845f   // 1/sqrt(128)

typedef _Float16 f16;
typedef _Float16 f16x8 __attribute__((ext_vector_type(8)));
typedef float f32x4 __attribute__((ext_vector_type(4)));
typedef unsigned int u32x4 __attribute__((ext_vector_type(4)));

#define MFMA(a,b,c) __builtin_amdgcn_mfma_f32_16x16x32_f16(a,b,c,0,0,0)

// ------------------------------------------------------------------
// prep: column norms of sim_matrix (inverse, f64), sigmoid(gates)
// ------------------------------------------------------------------
__global__ __launch_bounds__(256) void prep_kernel(const float* __restrict__ sim,
    const float* __restrict__ gates, double* __restrict__ wninv, double* __restrict__ sigg){
  __shared__ double part[16][17];
  int tid = threadIdx.x;
  int col = tid & 15, grp = tid >> 4;
  double ssq = 0.0;
  for (int r = grp; r < C_; r += 16){ float v = sim[r*E_ + col]; ssq += (double)v*(double)v; }
  part[grp][col] = ssq;
  __syncthreads();
  if (tid < E_){
    double s = 0.0;
    #pragma unroll
    for (int g2 = 0; g2 < 16; g2++) s += part[g2][tid];
    wninv[tid] = 1.0 / fmax(sqrt(s), 1e-12);
    sigg[tid]  = 1.0 / (1.0 + exp(-(double)gates[tid]));
  }
}

// ------------------------------------------------------------------
// gating (f64 accumulation for bit-robust top-2 routing):
// logits -> relu/STE mask -> top2 fallback -> masked softmax
// emits per-expert token lists (list/listw) via atomic cursors
// ------------------------------------------------------------------
__global__ __launch_bounds__(256) void gate_kernel(const float* __restrict__ x,
    const float* __restrict__ sim, const double* __restrict__ wninv,
    const double* __restrict__ sigg, int* __restrict__ cnt,
    int* __restrict__ list, float* __restrict__ listw){
  int n = blockIdx.x; int tid = threadIdx.x;
  const float* xr = x + (size_t)n * C_;
  double dot[E_];
  #pragma unroll
  for (int e = 0; e < E_; e++) dot[e] = 0.0;
  double ssq = 0.0;
  for (int c = tid; c < C_; c += 256){
    float xv = xr[c];
    ssq += (double)xv*(double)xv;
    const float* sr = sim + (size_t)c*E_;
    #pragma unroll
    for (int e = 0; e < E_; e++) dot[e] += (double)(xv * sr[e]);
  }
  __shared__ double red[256][17];
  #pragma unroll
  for (int e = 0; e < E_; e++) red[tid][e] = dot[e];
  red[tid][16] = ssq;
  __syncthreads();
  for (int s = 128; s > 0; s >>= 1){
    if (tid < s){
      #pragma unroll
      for (int j = 0; j < 17; j++) red[tid][j] += red[tid+s][j];
    }
    __syncthreads();
  }
  if (tid == 0){
    double inv = 1.0 / fmax(sqrt(red[0][16]), 1e-12);
    double logit[E_]; bool mask[E_]; int active = 0;
    #pragma unroll
    for (int e = 0; e < E_; e++){
      logit[e] = red[0][e] * inv * wninv[e] - sigg[e];
      mask[e] = logit[e] > 0.0;
      if (mask[e]) active++;
    }
    if (active == 0){
      int i1 = -1, i2 = -1; double b1 = -1e300, b2 = -1e300;
      for (int e = 0; e < E_; e++){
        double v = logit[e];
        if (v > b1){ b2 = b1; i2 = i1; b1 = v; i1 = e; }
        else if (v > b2){ b2 = v; i2 = e; }
      }
      mask[i1] = true; mask[i2] = true;
    }
    double mx = -1e300;
    for (int e = 0; e < E_; e++){ if (mask[e]) mx = fmax(mx, fmax(logit[e], 0.0)); }
    double ex[E_]; double sum = 0.0;
    for (int e = 0; e < E_; e++){
      double gval = fmax(logit[e], 0.0);
      ex[e] = mask[e] ? exp(gval - mx) : 0.0;
      sum += ex[e];
    }
    double isum = 1.0 / sum;
    for (int e = 0; e < E_; e++){
      if (mask[e]){
        int p = atomicAdd(&cnt[e], 1);
        list[e*N_TOK + p]  = n;
        listw[e*N_TOK + p] = (float)(ex[e]*isum);
      }
    }
  }
}

// ------------------------------------------------------------------
// grouped QKV GEMM: per expert, gather token rows of x, GEMM vs
// q/k/v_proj[e] (fp16 MFMA, fp32 accum), weighted atomic scatter-add.
// tile: 64 tokens x 64 cols x BK=64, 4 waves (2x2 of 32x32)
// ------------------------------------------------------------------
#define LDA_ 72
__global__ __launch_bounds__(256) void qkv_gemm(const float* __restrict__ x,
    const float* __restrict__ qp, const float* __restrict__ kp, const float* __restrict__ vp,
    const int* __restrict__ cnt, const int* __restrict__ list, const float* __restrict__ listw,
    float* __restrict__ qkv){
  int e = blockIdx.z;
  int ce = cnt[e];
  int m0 = blockIdx.x * 64;
  if (m0 >= ce) return;
  int zz = blockIdx.y;
  int proj = zz >> 1;
  int nb0 = (zz & 1) * 64;
  const float* W = (proj == 0 ? qp : (proj == 1 ? kp : vp)) + (size_t)e * C_ * H_;
  __shared__ __align__(16) f16 a_s[64*LDA_];
  __shared__ __align__(16) f16 b_s[64*LDA_];
  int tid = threadIdx.x;
  int l = tid & 63, wv = tid >> 6;
  int wm = wv >> 1, wn = wv & 1;
  int g = l >> 4, c = l & 15;
  int toks[16];
  #pragma unroll
  for (int i = 0; i < 16; i++){
    int gr = m0 + (tid >> 6) + 4*i;
    toks[i] = (gr < ce) ? list[e*N_TOK + gr] : 0;
  }
  f32x4 acc[2][2];
  #pragma unroll
  for (int m = 0; m < 2; m++)
    #pragma unroll
    for (int n2 = 0; n2 < 2; n2++) acc[m][n2] = (f32x4){0.f,0.f,0.f,0.f};

  for (int k0 = 0; k0 < C_; k0 += 64){
    int kk = tid & 63;
    #pragma unroll
    for (int i = 0; i < 16; i++){
      int r = (tid >> 6) + 4*i;
      a_s[r*LDA_ + kk] = (f16)x[(size_t)toks[i]*C_ + k0 + kk];
    }
    int nn = tid & 63;
    #pragma unroll
    for (int i = 0; i < 16; i++){
      int kr = (tid >> 6) + 4*i;
      b_s[nn*LDA_ + kr] = (f16)W[(size_t)(k0 + kr)*H_ + nb0 + nn];
    }
    __syncthreads();
    #pragma unroll
    for (int ks = 0; ks < 2; ks++){
      f16x8 af[2], bfr[2];
      #pragma unroll
      for (int m = 0; m < 2; m++)
        af[m] = *(const f16x8*)&a_s[(wm*32 + m*16 + c)*LDA_ + ks*32 + 8*g];
      #pragma unroll
      for (int n2 = 0; n2 < 2; n2++)
        bfr[n2] = *(const f16x8*)&b_s[(wn*32 + n2*16 + c)*LDA_ + ks*32 + 8*g];
      #pragma unroll
      for (int m = 0; m < 2; m++)
        #pragma unroll
        for (int n2 = 0; n2 < 2; n2++)
          acc[m][n2] = MFMA(af[m], bfr[n2], acc[m][n2]);
    }
    __syncthreads();
  }
  #pragma unroll
  for (int m = 0; m < 2; m++){
    #pragma unroll
    for (int i = 0; i < 4; i++){
      int gr = m0 + wm*32 + m*16 + 4*g + i;
      if (gr < ce){
        int tok  = list[e*N_TOK + gr];
        float w  = listw[e*N_TOK + gr];
        #pragma unroll
        for (int n2 = 0; n2 < 2; n2++){
          int col = nb0 + wn*32 + n2*16 + c;
          atomicAdd(&qkv[(size_t)tok*384 + proj*H_ + col], w * acc[m][n2][i]);
        }
      }
    }
  }
}

// ------------------------------------------------------------------
// RoPE on q,k halves of qkv buffer; emit fp16 q/k/v arrays
// ------------------------------------------------------------------
__global__ __launch_bounds__(192) void rope_kernel(const float* __restrict__ qkv,
    const int* __restrict__ pos_ids, f16* __restrict__ qh, f16* __restrict__ kh,
    f16* __restrict__ vh){
  int n = blockIdx.x; int tid = threadIdx.x;
  const float* row = qkv + (size_t)n * 384;
  if (tid < 128){
    int isK = tid >> 6, j = tid & 63;
    const float* src = row + isK*H_;
    float a = src[j], b = src[j+64];
    int pos = pos_ids[n & (T_-1)];
    // inv_freq = 10000^(-j/64) = 2^(-j*log2(10000)/64)
    float freq = exp2f(-(float)j * 0.20762050593046015f);
    float ang = (float)pos * freq;
    float s, cc;
    sincosf(ang, &s, &cc);
    f16* dst = isK ? kh : qh;
    dst[(size_t)n*H_ + j]      = (f16)(a*cc - b*s);
    dst[(size_t)n*H_ + j + 64] = (f16)(b*cc + a*s);
  } else {
    int j = (tid - 128)*2;
    vh[(size_t)n*H_ + j]     = (f16)row[256 + j];
    vh[(size_t)n*H_ + j + 1] = (f16)row[256 + j + 1];
  }
}

// ------------------------------------------------------------------
// flash attention, causal, D=128. Block = 32 q-rows (2 waves of 16),
// k-tiles of 64, online softmax, fp16 MFMA / fp32 accum.
// ------------------------------------------------------------------
#define LDK_ 136
#define LDV_ 72
__global__ __launch_bounds__(128) void attn_kernel(const f16* __restrict__ qh,
    const f16* __restrict__ kh, const f16* __restrict__ vh, f16* __restrict__ ah){
  int bid = blockIdx.x;
  int b = bid >> 6, qt = bid & 63;
  int q0 = qt*32, nbase = b*T_;
  __shared__ __align__(16) f16 q_s[32*LDK_];
  __shared__ __align__(16) f16 k_s[64*LDK_];
  __shared__ __align__(16) f16 v_s[128*LDV_];   // V^T: [dim][token]
  __shared__ __align__(16) f16 p_s[2*16*LDV_];
  int tid = threadIdx.x;
  int l = tid & 63, w = tid >> 6;
  int g = l >> 4, c = l & 15;
  #pragma unroll
  for (int i = 0; i < 4; i++){
    int slot = tid + 128*i;
    int ch = slot & 15, r = slot >> 4;
    *(u32x4*)&q_s[r*LDK_ + ch*8] = *(const u32x4*)&qh[((size_t)(nbase + q0 + r))*H_ + ch*8];
  }
  f32x4 oacc[8];
  #pragma unroll
  for (int nb = 0; nb < 8; nb++) oacc[nb] = (f32x4){0,0,0,0};
  float m_run[4], l_run[4];
  #pragma unroll
  for (int i = 0; i < 4; i++){ m_run[i] = -1e30f; l_run[i] = 0.f; }
  int nk = (q0 + 31)/64 + 1;
  for (int kt = 0; kt < nk; kt++){
    int kb = kt*64;
    __syncthreads();
    #pragma unroll
    for (int i = 0; i < 8; i++){
      int slot = tid + 128*i;
      int ch = slot & 15, r = slot >> 4;
      *(u32x4*)&k_s[r*LDK_ + ch*8] = *(const u32x4*)&kh[((size_t)(nbase + kb + r))*H_ + ch*8];
    }
    #pragma unroll
    for (int i = 0; i < 8; i++){
      int slot = tid + 128*i;
      int tok = slot & 63, ch = slot >> 6;
      f16x8 raw = *(const f16x8*)&vh[((size_t)(nbase + kb + tok))*H_ + ch*8];
      #pragma unroll
      for (int j = 0; j < 8; j++) v_s[(ch*8 + j)*LDV_ + tok] = raw[j];
    }
    __syncthreads();
    f32x4 sacc[4];
    #pragma unroll
    for (int f = 0; f < 4; f++) sacc[f] = (f32x4){0,0,0,0};
    #pragma unroll
    for (int ks = 0; ks < 4; ks++){
      f16x8 qf = *(const f16x8*)&q_s[(w*16 + c)*LDK_ + ks*32 + 8*g];
      #pragma unroll
      for (int f = 0; f < 4; f++){
        f16x8 kf = *(const f16x8*)&k_s[(f*16 + c)*LDK_ + ks*32 + 8*g];
        sacc[f] = MFMA(qf, kf, sacc[f]);
      }
    }
    float tm[4];
    #pragma unroll
    for (int i = 0; i < 4; i++) tm[i] = -1e30f;
    #pragma unroll
    for (int f = 0; f < 4; f++){
      int kg = kb + f*16 + c;
      #pragma unroll
      for (int i = 0; i < 4; i++){
        int qg = q0 + w*16 + 4*g + i;
        float s = sacc[f][i] * SCALE_;
        if (kg > qg) s = -1e30f;
        sacc[f][i] = s;
        tm[i] = fmaxf(tm[i], s);
      }
    }
    #pragma unroll
    for (int i = 0; i < 4; i++){
      #pragma unroll
      for (int d = 1; d <= 8; d <<= 1) tm[i] = fmaxf(tm[i], __shfl_xor(tm[i], d));
      float mn = fmaxf(m_run[i], tm[i]);
      float al = __expf(m_run[i] - mn);
      m_run[i] = mn;
      l_run[i] *= al;
      #pragma unroll
      for (int nb = 0; nb < 8; nb++) oacc[nb][i] *= al;
    }
    float rs[4] = {0.f,0.f,0.f,0.f};
    #pragma unroll
    for (int f = 0; f < 4; f++){
      #pragma unroll
      for (int i = 0; i < 4; i++){
        float p = __expf(sacc[f][i] - m_run[i]);
        rs[i] += p;
        p_s[w*16*LDV_ + (4*g + i)*LDV_ + f*16 + c] = (f16)p;
      }
    }
    #pragma unroll
    for (int i = 0; i < 4; i++){
      #pragma unroll
      for (int d = 1; d <= 8; d <<= 1) rs[i] += __shfl_xor(rs[i], d);
      l_run[i] += rs[i];
    }
    #pragma unroll
    for (int ks = 0; ks < 2; ks++){
      f16x8 pf = *(const f16x8*)&p_s[w*16*LDV_ + c*LDV_ + ks*32 + 8*g];
      #pragma unroll
      for (int nb = 0; nb < 8; nb++){
        f16x8 vf = *(const f16x8*)&v_s[(c + 16*nb)*LDV_ + ks*32 + 8*g];
        oacc[nb] = MFMA(pf, vf, oacc[nb]);
      }
    }
  }
  #pragma unroll
  for (int i = 0; i < 4; i++){
    float inv = 1.f / l_run[i];
    int qg = q0 + w*16 + 4*g + i;
    #pragma unroll
    for (int nb = 0; nb < 8; nb++)
      ah[((size_t)(nbase + qg))*H_ + c + 16*nb] = (f16)(oacc[nb][i] * inv);
  }
}

// ------------------------------------------------------------------
// grouped O GEMM: gather attn rows (pre-scaled by routing weight),
// GEMM vs o_proj[e] [128 x 2048], atomic scatter-add into out.
// ------------------------------------------------------------------
#define LDO_ 136
__global__ __launch_bounds__(256) void o_gemm(const f16* __restrict__ ah,
    const float* __restrict__ op, const int* __restrict__ cnt,
    const int* __restrict__ list, const float* __restrict__ listw,
    float* __restrict__ out){
  int e = blockIdx.z;
  int ce = cnt[e];
  int m0 = blockIdx.x * 64;
  if (m0 >= ce) return;
  int n0 = blockIdx.y * 64;
  __shared__ __align__(16) f16 a_s[64*LDO_];
  __shared__ __align__(16) f16 b_s[64*LDO_];
  int tid = threadIdx.x;
  int l = tid & 63, wv = tid >> 6;
  int wm = wv >> 1, wn = wv & 1;
  int g = l >> 4, c = l & 15;
  #pragma unroll
  for (int i = 0; i < 4; i++){
    int slot = tid + 256*i;
    int ch = slot & 15, r = slot >> 4;
    int gr = m0 + r;
    int tok = 0; float wgt = 0.f;
    if (gr < ce){ tok = list[e*N_TOK + gr]; wgt = listw[e*N_TOK + gr]; }
    f16x8 raw = *(const f16x8*)&ah[(size_t)tok*H_ + ch*8];
    f16x8 vv;
    #pragma unroll
    for (int j = 0; j < 8; j++) vv[j] = (f16)(wgt * (float)raw[j]);
    *(f16x8*)&a_s[r*LDO_ + ch*8] = vv;
  }
  int nn = tid & 63;
  #pragma unroll
  for (int i = 0; i < 32; i++){
    int k = (tid >> 6) + 4*i;
    b_s[nn*LDO_ + k] = (f16)op[(size_t)e*H_*C_ + (size_t)k*C_ + n0 + nn];
  }
  __syncthreads();
  f32x4 acc[2][2];
  #pragma unroll
  for (int m = 0; m < 2; m++)
    #pragma unroll
    for (int n2 = 0; n2 < 2; n2++) acc[m][n2] = (f32x4){0.f,0.f,0.f,0.f};
  #pragma unroll
  for (int ks = 0; ks < 4; ks++){
    f16x8 af[2], bfr[2];
    #pragma unroll
    for (int m = 0; m < 2; m++)
      af[m] = *(const f16x8*)&a_s[(wm*32 + m*16 + c)*LDO_ + ks*32 + 8*g];
    #pragma unroll
    for (int n2 = 0; n2 < 2; n2++)
      bfr[n2] = *(const f16x8*)&b_s[(wn*32 + n2*16 + c)*LDO_ + ks*32 + 8*g];
    #pragma unroll
    for (int m = 0; m < 2; m++)
      #pragma unroll
      for (int n2 = 0; n2 < 2; n2++)
        acc[m][n2] = MFMA(af[m], bfr[n2], acc[m][n2]);
  }
  #pragma unroll
  for (int m = 0; m < 2; m++){
    #pragma unroll
    for (int i = 0; i < 4; i++){
      int gr = m0 + wm*32 + m*16 + 4*g + i;
      if (gr < ce){
        int tok = list[e*N_TOK + gr];
        #pragma unroll
        for (int n2 = 0; n2 < 2; n2++){
          atomicAdd(&out[(size_t)tok*C_ + n0 + wn*32 + n2*16 + c], acc[m][n2][i]);
        }
      }
    }
  }
}

// ------------------------------------------------------------------
extern "C" void kernel_launch(void* const* d_in, const int* in_sizes, int n_in,
                              void* d_out, int out_size, void* d_ws, size_t ws_size,
                              hipStream_t stream){
  const float* hs    = (const float*)d_in[0];
  const int*   pos   = (const int*)d_in[1];
  const float* sim   = (const float*)d_in[2];
  const float* gates = (const float*)d_in[3];
  const float* qp    = (const float*)d_in[4];
  const float* kp    = (const float*)d_in[5];
  const float* vp    = (const float*)d_in[6];
  const float* op    = (const float*)d_in[7];
  float* out = (float*)d_out;
  char* ws = (char*)d_ws;
  // workspace layout (16B-aligned offsets)
  int*    cnt   = (int*)(ws + 0);          // 16 ints
  double* wninv = (double*)(ws + 64);      // 16 f64
  double* sigg  = (double*)(ws + 192);     // 16 f64
  int*    list  = (int*)(ws + 320);        // 16*8192 int
  float*  listw = (float*)(ws + 320 + 524288);
  float*  qkv   = (float*)(ws + 1048896);  // [8192][384] f32
  f16* qh = (f16*)(ws + 13631808);         // [8192][128] f16
  f16* kh = (f16*)(ws + 15728960);
  f16* vh = (f16*)(ws + 17826112);
  f16* ah = (f16*)(ws + 19923264);

  hipMemsetAsync(cnt, 0, 64, stream);
  hipMemsetAsync(qkv, 0, (size_t)N_TOK*384*4, stream);
  hipMemsetAsync(out, 0, (size_t)N_TOK*C_*4, stream);

  prep_kernel<<<1, 256, 0, stream>>>(sim, gates, wninv, sigg);
  gate_kernel<<<N_TOK, 256, 0, stream>>>(hs, sim, wninv, sigg, cnt, list, listw);
  qkv_gemm<<<dim3(128, 6, 16), 256, 0, stream>>>(hs, qp, kp, vp, cnt, list, listw, qkv);
  rope_kernel<<<N_TOK, 192, 0, stream>>>(qkv, pos, qh, kh, vh);
  attn_kernel<<<256, 128, 0, stream>>>(qh, kh, vh, ah);
  o_gemm<<<dim3(128, 32, 16), 256, 0, stream>>>(ah, op, cnt, list, listw, out);
}

// Round 3
// 827.639 us; speedup vs baseline: 2.0502x; 2.0502x over previous
//
#include <hip/hip_runtime.h>
#include <hip/hip_fp16.h>

#define T_ 2048
#define C_ 2048
#define H_ 128
#define E_ 16
#define N_TOK 8192
#define SCALE_ 0.08838834764831845f   // 1/sqrt(128)

typedef _Float16 f16;
typedef _Float16 f16x4 __attribute__((ext_vector_type(4)));
typedef _Float16 f16x8 __attribute__((ext_vector_type(8)));
typedef float f32x4 __attribute__((ext_vector_type(4)));
typedef unsigned int u32x4 __attribute__((ext_vector_type(4)));

#define MFMA(a,b,c) __builtin_amdgcn_mfma_f32_16x16x32_f16(a,b,c,0,0,0)

// ------------------------------------------------------------------
// prep: column norms of sim_matrix (inverse, f64), sigmoid(gates)
// ------------------------------------------------------------------
__global__ __launch_bounds__(256) void prep_kernel(const float* __restrict__ sim,
    const float* __restrict__ gates, double* __restrict__ wninv, double* __restrict__ sigg){
  __shared__ double part[16][17];
  int tid = threadIdx.x;
  int col = tid & 15, grp = tid >> 4;
  double ssq = 0.0;
  for (int r = grp; r < C_; r += 16){ float v = sim[r*E_ + col]; ssq += (double)v*(double)v; }
  part[grp][col] = ssq;
  __syncthreads();
  if (tid < E_){
    double s = 0.0;
    #pragma unroll
    for (int g2 = 0; g2 < 16; g2++) s += part[g2][tid];
    wninv[tid] = 1.0 / fmax(sqrt(s), 1e-12);
    sigg[tid]  = 1.0 / (1.0 + exp(-(double)gates[tid]));
  }
}

// ------------------------------------------------------------------
// converts: x -> f16; q/k/v_proj -> f16 transposed [e][384][2048];
// o_proj -> f16 transposed [e][2048][128]
// ------------------------------------------------------------------
__global__ __launch_bounds__(256) void conv_x(const float* __restrict__ x, f16* __restrict__ xh){
  for (int v = blockIdx.x*256 + threadIdx.x; v < N_TOK*C_/4; v += 4096*256){
    f32x4 a = *(const f32x4*)&x[(size_t)v*4];
    f16x4 h; h[0]=(f16)a[0]; h[1]=(f16)a[1]; h[2]=(f16)a[2]; h[3]=(f16)a[3];
    *(f16x4*)&xh[(size_t)v*4] = h;
  }
}

__global__ __launch_bounds__(256) void conv_w(const float* __restrict__ qp,
    const float* __restrict__ kp, const float* __restrict__ vp, f16* __restrict__ wT){
  int ep = blockIdx.z; int e = ep/3, proj = ep - 3*e;
  const float* W = (proj==0?qp:(proj==1?kp:vp)) + (size_t)e*C_*H_;
  int k0 = blockIdx.x*64, j0 = blockIdx.y*64;
  __shared__ float t[64][65];
  int tid = threadIdx.x;
  #pragma unroll
  for (int i = 0; i < 4; i++){
    int s = tid + 256*i;
    int r = s >> 4, c4 = (s & 15)*4;
    f32x4 a = *(const f32x4*)&W[(size_t)(k0+r)*H_ + j0 + c4];
    t[r][c4]=a[0]; t[r][c4+1]=a[1]; t[r][c4+2]=a[2]; t[r][c4+3]=a[3];
  }
  __syncthreads();
  #pragma unroll
  for (int i = 0; i < 4; i++){
    int s = tid + 256*i;
    int jj = s >> 4, k4 = (s & 15)*4;
    f16x4 h;
    h[0]=(f16)t[k4][jj]; h[1]=(f16)t[k4+1][jj]; h[2]=(f16)t[k4+2][jj]; h[3]=(f16)t[k4+3][jj];
    *(f16x4*)&wT[((size_t)e*384 + proj*128 + j0 + jj)*C_ + k0 + k4] = h;
  }
}

__global__ __launch_bounds__(256) void conv_o(const float* __restrict__ op, f16* __restrict__ oT){
  int e = blockIdx.z;
  int n0 = blockIdx.x*64, k0 = blockIdx.y*64;
  __shared__ float t[64][65];
  int tid = threadIdx.x;
  #pragma unroll
  for (int i = 0; i < 4; i++){
    int s = tid + 256*i;
    int r = s >> 4, c4 = (s & 15)*4;   // r: k, c4: n
    f32x4 a = *(const f32x4*)&op[(size_t)e*H_*C_ + (size_t)(k0+r)*C_ + n0 + c4];
    t[r][c4]=a[0]; t[r][c4+1]=a[1]; t[r][c4+2]=a[2]; t[r][c4+3]=a[3];
  }
  __syncthreads();
  #pragma unroll
  for (int i = 0; i < 4; i++){
    int s = tid + 256*i;
    int nn = s >> 4, k4 = (s & 15)*4;
    f16x4 h;
    h[0]=(f16)t[k4][nn]; h[1]=(f16)t[k4+1][nn]; h[2]=(f16)t[k4+2][nn]; h[3]=(f16)t[k4+3][nn];
    *(f16x4*)&oT[((size_t)e*C_ + n0 + nn)*H_ + k0 + k4] = h;
  }
}

// ------------------------------------------------------------------
// gating (f64 accumulation for bit-robust top-2 routing)
// ------------------------------------------------------------------
__global__ __launch_bounds__(256) void gate_kernel(const float* __restrict__ x,
    const float* __restrict__ sim, const double* __restrict__ wninv,
    const double* __restrict__ sigg, int* __restrict__ cnt,
    int* __restrict__ list, float* __restrict__ listw){
  int n = blockIdx.x; int tid = threadIdx.x;
  const float* xr = x + (size_t)n * C_;
  double dot[E_];
  #pragma unroll
  for (int e = 0; e < E_; e++) dot[e] = 0.0;
  double ssq = 0.0;
  for (int c = tid; c < C_; c += 256){
    float xv = xr[c];
    ssq += (double)xv*(double)xv;
    const float* sr = sim + (size_t)c*E_;
    #pragma unroll
    for (int e = 0; e < E_; e++) dot[e] += (double)(xv * sr[e]);
  }
  __shared__ double red[256][17];
  #pragma unroll
  for (int e = 0; e < E_; e++) red[tid][e] = dot[e];
  red[tid][16] = ssq;
  __syncthreads();
  for (int s = 128; s > 0; s >>= 1){
    if (tid < s){
      #pragma unroll
      for (int j = 0; j < 17; j++) red[tid][j] += red[tid+s][j];
    }
    __syncthreads();
  }
  if (tid == 0){
    double inv = 1.0 / fmax(sqrt(red[0][16]), 1e-12);
    double logit[E_]; bool mask[E_]; int active = 0;
    #pragma unroll
    for (int e = 0; e < E_; e++){
      logit[e] = red[0][e] * inv * wninv[e] - sigg[e];
      mask[e] = logit[e] > 0.0;
      if (mask[e]) active++;
    }
    if (active == 0){
      int i1 = -1, i2 = -1; double b1 = -1e300, b2 = -1e300;
      for (int e = 0; e < E_; e++){
        double v = logit[e];
        if (v > b1){ b2 = b1; i2 = i1; b1 = v; i1 = e; }
        else if (v > b2){ b2 = v; i2 = e; }
      }
      mask[i1] = true; mask[i2] = true;
    }
    double mx = -1e300;
    for (int e = 0; e < E_; e++){ if (mask[e]) mx = fmax(mx, fmax(logit[e], 0.0)); }
    double ex[E_]; double sum = 0.0;
    for (int e = 0; e < E_; e++){
      double gval = fmax(logit[e], 0.0);
      ex[e] = mask[e] ? exp(gval - mx) : 0.0;
      sum += ex[e];
    }
    double isum = 1.0 / sum;
    for (int e = 0; e < E_; e++){
      if (mask[e]){
        int p = atomicAdd(&cnt[e], 1);
        list[e*N_TOK + p]  = n;
        listw[e*N_TOK + p] = (float)(ex[e]*isum);
      }
    }
  }
}

// ------------------------------------------------------------------
// tile list: for each expert, one entry per 64-token m-tile
// ------------------------------------------------------------------
__global__ __launch_bounds__(64) void tile_builder(const int* __restrict__ cnt,
    int* __restrict__ tlist, int* __restrict__ ntile){
  __shared__ int nts[E_];
  int tid = threadIdx.x;
  if (tid < E_) nts[tid] = (cnt[tid] + 63) >> 6;
  __syncthreads();
  if (tid < E_){
    int base = 0;
    for (int e = 0; e < tid; e++) base += nts[e];
    int nt = nts[tid];
    for (int t = 0; t < nt; t++) tlist[base + t] = (tid << 8) | t;
    if (tid == E_-1) *ntile = base + nt;
  }
}

// ------------------------------------------------------------------
// grouped QKV GEMM v2: tile-list driven, 64x128xBK128, f16x8 staging,
// 4 waves (wave-tile 32x64), weighted fp32 atomic scatter.
// ------------------------------------------------------------------
#define LDT 136
__global__ __launch_bounds__(256) void qkv_gemm(const f16* __restrict__ xh,
    const f16* __restrict__ wT, const int* __restrict__ cnt,
    const int* __restrict__ list, const float* __restrict__ listw,
    const int* __restrict__ tlist, const int* __restrict__ ntile,
    float* __restrict__ qkv){
  __shared__ __align__(16) f16 a_s[64*LDT];
  __shared__ __align__(16) f16 b_s[128*LDT];
  __shared__ int tok_s[64];
  __shared__ float wgt_s[64];
  int nitems = (*ntile) * 3;
  int tid = threadIdx.x;
  int l = tid & 63, wv = tid >> 6;
  int wm = wv >> 1, wn = wv & 1;
  int g = l >> 4, c = l & 15;
  for (int w = blockIdx.x; w < nitems; w += gridDim.x){
    int tile = w / 3, nb = w - tile*3;
    int ent = tlist[tile];
    int e = ent >> 8, mt = ent & 255;
    int ce = cnt[e];
    int m0 = mt * 64;
    if (tid < 64){
      int gr = m0 + tid;
      tok_s[tid] = (gr < ce) ? list[e*N_TOK + gr] : 0;
      wgt_s[tid] = (gr < ce) ? listw[e*N_TOK + gr] : 0.f;
    }
    __syncthreads();
    f32x4 acc[2][4];
    #pragma unroll
    for (int m = 0; m < 2; m++)
      #pragma unroll
      for (int n = 0; n < 4; n++) acc[m][n] = (f32x4){0.f,0.f,0.f,0.f};
    const f16* Bbase = wT + ((size_t)e*384 + nb*128)*C_;
    for (int k0 = 0; k0 < C_; k0 += 128){
      #pragma unroll
      for (int i = 0; i < 4; i++){
        int s = tid + 256*i;
        int r = s >> 4, cs = (s & 15)*8;
        f16x8 v = *(const f16x8*)&xh[(size_t)tok_s[r]*C_ + k0 + cs];
        *(f16x8*)&a_s[r*LDT + cs] = v;
      }
      #pragma unroll
      for (int i = 0; i < 8; i++){
        int s = tid + 256*i;
        int j = s >> 4, cs = (s & 15)*8;
        f16x8 v = *(const f16x8*)&Bbase[(size_t)j*C_ + k0 + cs];
        *(f16x8*)&b_s[j*LDT + cs] = v;
      }
      __syncthreads();
      #pragma unroll
      for (int ks = 0; ks < 4; ks++){
        f16x8 af[2], bf[4];
        #pragma unroll
        for (int m = 0; m < 2; m++)
          af[m] = *(const f16x8*)&a_s[(wm*32 + m*16 + c)*LDT + ks*32 + 8*g];
        #pragma unroll
        for (int n = 0; n < 4; n++)
          bf[n] = *(const f16x8*)&b_s[(wn*64 + n*16 + c)*LDT + ks*32 + 8*g];
        #pragma unroll
        for (int m = 0; m < 2; m++)
          #pragma unroll
          for (int n = 0; n < 4; n++)
            acc[m][n] = MFMA(af[m], bf[n], acc[m][n]);
      }
      __syncthreads();
    }
    #pragma unroll
    for (int m = 0; m < 2; m++){
      #pragma unroll
      for (int i = 0; i < 4; i++){
        int row = wm*32 + m*16 + 4*g + i;
        int gr = m0 + row;
        if (gr < ce){
          int tok = tok_s[row]; float wgt = wgt_s[row];
          #pragma unroll
          for (int n = 0; n < 4; n++){
            int col = nb*128 + wn*64 + n*16 + c;
            atomicAdd(&qkv[(size_t)tok*384 + col], wgt*acc[m][n][i]);
          }
        }
      }
    }
    __syncthreads();
  }
}

// ------------------------------------------------------------------
// RoPE on q,k halves of qkv buffer; emit fp16 q/k/v arrays
// ------------------------------------------------------------------
__global__ __launch_bounds__(192) void rope_kernel(const float* __restrict__ qkv,
    const int* __restrict__ pos_ids, f16* __restrict__ qh, f16* __restrict__ kh,
    f16* __restrict__ vh){
  int n = blockIdx.x; int tid = threadIdx.x;
  const float* row = qkv + (size_t)n * 384;
  if (tid < 128){
    int isK = tid >> 6, j = tid & 63;
    const float* src = row + isK*H_;
    float a = src[j], b = src[j+64];
    int pos = pos_ids[n & (T_-1)];
    float freq = exp2f(-(float)j * 0.20762050593046015f);
    float ang = (float)pos * freq;
    float s, cc;
    sincosf(ang, &s, &cc);
    f16* dst = isK ? kh : qh;
    dst[(size_t)n*H_ + j]      = (f16)(a*cc - b*s);
    dst[(size_t)n*H_ + j + 64] = (f16)(b*cc + a*s);
  } else {
    int j = (tid - 128)*2;
    vh[(size_t)n*H_ + j]     = (f16)row[256 + j];
    vh[(size_t)n*H_ + j + 1] = (f16)row[256 + j + 1];
  }
}

// ------------------------------------------------------------------
// flash attention, causal, D=128 (unchanged from round 2)
// ------------------------------------------------------------------
#define LDK_ 136
#define LDV_ 72
__global__ __launch_bounds__(128) void attn_kernel(const f16* __restrict__ qh,
    const f16* __restrict__ kh, const f16* __restrict__ vh, f16* __restrict__ ah){
  int bid = blockIdx.x;
  int b = bid >> 6, qt = bid & 63;
  int q0 = qt*32, nbase = b*T_;
  __shared__ __align__(16) f16 q_s[32*LDK_];
  __shared__ __align__(16) f16 k_s[64*LDK_];
  __shared__ __align__(16) f16 v_s[128*LDV_];
  __shared__ __align__(16) f16 p_s[2*16*LDV_];
  int tid = threadIdx.x;
  int l = tid & 63, w = tid >> 6;
  int g = l >> 4, c = l & 15;
  #pragma unroll
  for (int i = 0; i < 4; i++){
    int slot = tid + 128*i;
    int ch = slot & 15, r = slot >> 4;
    *(u32x4*)&q_s[r*LDK_ + ch*8] = *(const u32x4*)&qh[((size_t)(nbase + q0 + r))*H_ + ch*8];
  }
  f32x4 oacc[8];
  #pragma unroll
  for (int nb = 0; nb < 8; nb++) oacc[nb] = (f32x4){0,0,0,0};
  float m_run[4], l_run[4];
  #pragma unroll
  for (int i = 0; i < 4; i++){ m_run[i] = -1e30f; l_run[i] = 0.f; }
  int nk = (q0 + 31)/64 + 1;
  for (int kt = 0; kt < nk; kt++){
    int kb = kt*64;
    __syncthreads();
    #pragma unroll
    for (int i = 0; i < 8; i++){
      int slot = tid + 128*i;
      int ch = slot & 15, r = slot >> 4;
      *(u32x4*)&k_s[r*LDK_ + ch*8] = *(const u32x4*)&kh[((size_t)(nbase + kb + r))*H_ + ch*8];
    }
    #pragma unroll
    for (int i = 0; i < 8; i++){
      int slot = tid + 128*i;
      int tok = slot & 63, ch = slot >> 6;
      f16x8 raw = *(const f16x8*)&vh[((size_t)(nbase + kb + tok))*H_ + ch*8];
      #pragma unroll
      for (int j = 0; j < 8; j++) v_s[(ch*8 + j)*LDV_ + tok] = raw[j];
    }
    __syncthreads();
    f32x4 sacc[4];
    #pragma unroll
    for (int f = 0; f < 4; f++) sacc[f] = (f32x4){0,0,0,0};
    #pragma unroll
    for (int ks = 0; ks < 4; ks++){
      f16x8 qf = *(const f16x8*)&q_s[(w*16 + c)*LDK_ + ks*32 + 8*g];
      #pragma unroll
      for (int f = 0; f < 4; f++){
        f16x8 kf = *(const f16x8*)&k_s[(f*16 + c)*LDK_ + ks*32 + 8*g];
        sacc[f] = MFMA(qf, kf, sacc[f]);
      }
    }
    float tm[4];
    #pragma unroll
    for (int i = 0; i < 4; i++) tm[i] = -1e30f;
    #pragma unroll
    for (int f = 0; f < 4; f++){
      int kg = kb + f*16 + c;
      #pragma unroll
      for (int i = 0; i < 4; i++){
        int qg = q0 + w*16 + 4*g + i;
        float s = sacc[f][i] * SCALE_;
        if (kg > qg) s = -1e30f;
        sacc[f][i] = s;
        tm[i] = fmaxf(tm[i], s);
      }
    }
    #pragma unroll
    for (int i = 0; i < 4; i++){
      #pragma unroll
      for (int d = 1; d <= 8; d <<= 1) tm[i] = fmaxf(tm[i], __shfl_xor(tm[i], d));
      float mn = fmaxf(m_run[i], tm[i]);
      float al = __expf(m_run[i] - mn);
      m_run[i] = mn;
      l_run[i] *= al;
      #pragma unroll
      for (int nb = 0; nb < 8; nb++) oacc[nb][i] *= al;
    }
    float rs[4] = {0.f,0.f,0.f,0.f};
    #pragma unroll
    for (int f = 0; f < 4; f++){
      #pragma unroll
      for (int i = 0; i < 4; i++){
        float p = __expf(sacc[f][i] - m_run[i]);
        rs[i] += p;
        p_s[w*16*LDV_ + (4*g + i)*LDV_ + f*16 + c] = (f16)p;
      }
    }
    #pragma unroll
    for (int i = 0; i < 4; i++){
      #pragma unroll
      for (int d = 1; d <= 8; d <<= 1) rs[i] += __shfl_xor(rs[i], d);
      l_run[i] += rs[i];
    }
    #pragma unroll
    for (int ks = 0; ks < 2; ks++){
      f16x8 pf = *(const f16x8*)&p_s[w*16*LDV_ + c*LDV_ + ks*32 + 8*g];
      #pragma unroll
      for (int nb = 0; nb < 8; nb++){
        f16x8 vf = *(const f16x8*)&v_s[(c + 16*nb)*LDV_ + ks*32 + 8*g];
        oacc[nb] = MFMA(pf, vf, oacc[nb]);
      }
    }
  }
  #pragma unroll
  for (int i = 0; i < 4; i++){
    float inv = 1.f / l_run[i];
    int qg = q0 + w*16 + 4*g + i;
    #pragma unroll
    for (int nb = 0; nb < 8; nb++)
      ah[((size_t)(nbase + qg))*H_ + c + 16*nb] = (f16)(oacc[nb][i] * inv);
  }
}

// ------------------------------------------------------------------
// grouped O GEMM v2: tile-list driven, K=128 single stage,
// A pre-scaled by routing weight, atomic scatter into out.
// ------------------------------------------------------------------
__global__ __launch_bounds__(256) void o_gemm(const f16* __restrict__ ah,
    const f16* __restrict__ oT, const int* __restrict__ cnt,
    const int* __restrict__ list, const float* __restrict__ listw,
    const int* __restrict__ tlist, const int* __restrict__ ntile,
    float* __restrict__ out){
  __shared__ __align__(16) f16 a_s[64*LDT];
  __shared__ __align__(16) f16 b_s[128*LDT];
  __shared__ int tok_s[64];
  __shared__ float wgt_s[64];
  int nitems = (*ntile) * 16;
  int tid = threadIdx.x;
  int l = tid & 63, wv = tid >> 6;
  int wm = wv >> 1, wn = wv & 1;
  int g = l >> 4, c = l & 15;
  for (int w = blockIdx.x; w < nitems; w += gridDim.x){
    int tile = w >> 4, nbt = w & 15;
    int ent = tlist[tile];
    int e = ent >> 8, mt = ent & 255;
    int ce = cnt[e];
    int m0 = mt * 64, n0 = nbt * 128;
    if (tid < 64){
      int gr = m0 + tid;
      tok_s[tid] = (gr < ce) ? list[e*N_TOK + gr] : 0;
      wgt_s[tid] = (gr < ce) ? listw[e*N_TOK + gr] : 0.f;
    }
    __syncthreads();
    #pragma unroll
    for (int i = 0; i < 4; i++){
      int s = tid + 256*i;
      int r = s >> 4, cs = (s & 15)*8;
      f16x8 v = *(const f16x8*)&ah[(size_t)tok_s[r]*H_ + cs];
      float wgt = wgt_s[r];
      f16x8 o;
      #pragma unroll
      for (int j = 0; j < 8; j++) o[j] = (f16)((float)v[j]*wgt);
      *(f16x8*)&a_s[r*LDT + cs] = o;
    }
    #pragma unroll
    for (int i = 0; i < 8; i++){
      int s = tid + 256*i;
      int j = s >> 4, cs = (s & 15)*8;
      f16x8 v = *(const f16x8*)&oT[((size_t)e*C_ + n0 + j)*H_ + cs];
      *(f16x8*)&b_s[j*LDT + cs] = v;
    }
    __syncthreads();
    f32x4 acc[2][4];
    #pragma unroll
    for (int m = 0; m < 2; m++)
      #pragma unroll
      for (int n = 0; n < 4; n++) acc[m][n] = (f32x4){0.f,0.f,0.f,0.f};
    #pragma unroll
    for (int ks = 0; ks < 4; ks++){
      f16x8 af[2], bf[4];
      #pragma unroll
      for (int m = 0; m < 2; m++)
        af[m] = *(const f16x8*)&a_s[(wm*32 + m*16 + c)*LDT + ks*32 + 8*g];
      #pragma unroll
      for (int n = 0; n < 4; n++)
        bf[n] = *(const f16x8*)&b_s[(wn*64 + n*16 + c)*LDT + ks*32 + 8*g];
      #pragma unroll
      for (int m = 0; m < 2; m++)
        #pragma unroll
        for (int n = 0; n < 4; n++)
          acc[m][n] = MFMA(af[m], bf[n], acc[m][n]);
    }
    #pragma unroll
    for (int m = 0; m < 2; m++){
      #pragma unroll
      for (int i = 0; i < 4; i++){
        int row = wm*32 + m*16 + 4*g + i;
        int gr = m0 + row;
        if (gr < ce){
          int tok = tok_s[row];
          #pragma unroll
          for (int n = 0; n < 4; n++){
            int col = n0 + wn*64 + n*16 + c;
            atomicAdd(&out[(size_t)tok*C_ + col], acc[m][n][i]);
          }
        }
      }
    }
    __syncthreads();
  }
}

// ------------------------------------------------------------------
extern "C" void kernel_launch(void* const* d_in, const int* in_sizes, int n_in,
                              void* d_out, int out_size, void* d_ws, size_t ws_size,
                              hipStream_t stream){
  const float* hs    = (const float*)d_in[0];
  const int*   pos   = (const int*)d_in[1];
  const float* sim   = (const float*)d_in[2];
  const float* gates = (const float*)d_in[3];
  const float* qp    = (const float*)d_in[4];
  const float* kp    = (const float*)d_in[5];
  const float* vp    = (const float*)d_in[6];
  const float* op    = (const float*)d_in[7];
  float* out = (float*)d_out;
  char* ws = (char*)d_ws;
  // workspace layout
  int*    cnt   = (int*)(ws + 0);               // 16 int
  int*    ntile = (int*)(ws + 64);              // 1 int
  double* wninv = (double*)(ws + 128);          // 16 f64
  double* sigg  = (double*)(ws + 256);          // 16 f64
  int*    tlist = (int*)(ws + 512);             // 2048 int
  int*    list  = (int*)(ws + 8704);            // 16*8192 int
  float*  listw = (float*)(ws + 532992);        // 16*8192 f32
  f16*    xh    = (f16*)(ws + 1057280);         // [8192][2048]
  f16*    wT    = (f16*)(ws + 34611712);        // [16][384][2048]
  f16*    oT    = (f16*)(ws + 59777536);        // [16][2048][128]
  float*  qkv   = (float*)(ws + 68166144);      // [8192][384] f32
  f16*    qh    = (f16*)(ws + 80749056);        // [8192][128]
  f16*    kh    = (f16*)(ws + 82846208);
  f16*    vh    = (f16*)(ws + 84943360);
  f16*    ah    = (f16*)(ws + 87040512);        // ends 89137664

  hipMemsetAsync(cnt, 0, 64, stream);
  hipMemsetAsync(qkv, 0, (size_t)N_TOK*384*4, stream);
  hipMemsetAsync(out, 0, (size_t)N_TOK*C_*4, stream);

  prep_kernel<<<1, 256, 0, stream>>>(sim, gates, wninv, sigg);
  conv_x<<<4096, 256, 0, stream>>>(hs, xh);
  conv_w<<<dim3(32, 2, 48), 256, 0, stream>>>(qp, kp, vp, wT);
  conv_o<<<dim3(32, 2, 16), 256, 0, stream>>>(op, oT);
  gate_kernel<<<N_TOK, 256, 0, stream>>>(hs, sim, wninv, sigg, cnt, list, listw);
  tile_builder<<<1, 64, 0, stream>>>(cnt, tlist, ntile);
  qkv_gemm<<<1024, 256, 0, stream>>>(xh, wT, cnt, list, listw, tlist, ntile, qkv);
  rope_kernel<<<N_TOK, 192, 0, stream>>>(qkv, pos, qh, kh, vh);
  attn_kernel<<<256, 128, 0, stream>>>(qh, kh, vh, ah);
  o_gemm<<<2048, 256, 0, stream>>>(ah, oT, cnt, list, listw, tlist, ntile, out);
}

// Round 4
// 712.704 us; speedup vs baseline: 2.3809x; 1.1613x over previous
//
#include <hip/hip_runtime.h>
#include <hip/hip_fp16.h>

#define T_ 2048
#define C_ 2048
#define H_ 128
#define E_ 16
#define N_TOK 8192
#define SCALE_ 0.08838834764831845f   // 1/sqrt(128)

typedef _Float16 f16;
typedef _Float16 f16x4 __attribute__((ext_vector_type(4)));
typedef _Float16 f16x8 __attribute__((ext_vector_type(8)));
typedef float f32x4 __attribute__((ext_vector_type(4)));
typedef unsigned int u32x4 __attribute__((ext_vector_type(4)));

#define MFMA(a,b,c) __builtin_amdgcn_mfma_f32_16x16x32_f16(a,b,c,0,0,0)

// ------------------------------------------------------------------
// prep: column norms of sim_matrix (inverse, f64), sigmoid(gates)
// ------------------------------------------------------------------
__global__ __launch_bounds__(256) void prep_kernel(const float* __restrict__ sim,
    const float* __restrict__ gates, double* __restrict__ wninv, double* __restrict__ sigg){
  __shared__ double part[16][17];
  int tid = threadIdx.x;
  int col = tid & 15, grp = tid >> 4;
  double ssq = 0.0;
  for (int r = grp; r < C_; r += 16){ float v = sim[r*E_ + col]; ssq += (double)v*(double)v; }
  part[grp][col] = ssq;
  __syncthreads();
  if (tid < E_){
    double s = 0.0;
    #pragma unroll
    for (int g2 = 0; g2 < 16; g2++) s += part[g2][tid];
    wninv[tid] = 1.0 / fmax(sqrt(s), 1e-12);
    sigg[tid]  = 1.0 / (1.0 + exp(-(double)gates[tid]));
  }
}

// ------------------------------------------------------------------
// converts: x -> f16; q/k/v_proj -> f16 transposed [e][384][2048];
// o_proj -> f16 transposed [e][2048][128]
// ------------------------------------------------------------------
__global__ __launch_bounds__(256) void conv_x(const float* __restrict__ x, f16* __restrict__ xh){
  for (int v = blockIdx.x*256 + threadIdx.x; v < N_TOK*C_/4; v += 4096*256){
    f32x4 a = *(const f32x4*)&x[(size_t)v*4];
    f16x4 h; h[0]=(f16)a[0]; h[1]=(f16)a[1]; h[2]=(f16)a[2]; h[3]=(f16)a[3];
    *(f16x4*)&xh[(size_t)v*4] = h;
  }
}

__global__ __launch_bounds__(256) void conv_w(const float* __restrict__ qp,
    const float* __restrict__ kp, const float* __restrict__ vp, f16* __restrict__ wT){
  int ep = blockIdx.z; int e = ep/3, proj = ep - 3*e;
  const float* W = (proj==0?qp:(proj==1?kp:vp)) + (size_t)e*C_*H_;
  int k0 = blockIdx.x*64, j0 = blockIdx.y*64;
  __shared__ float t[64][65];
  int tid = threadIdx.x;
  #pragma unroll
  for (int i = 0; i < 4; i++){
    int s = tid + 256*i;
    int r = s >> 4, c4 = (s & 15)*4;
    f32x4 a = *(const f32x4*)&W[(size_t)(k0+r)*H_ + j0 + c4];
    t[r][c4]=a[0]; t[r][c4+1]=a[1]; t[r][c4+2]=a[2]; t[r][c4+3]=a[3];
  }
  __syncthreads();
  #pragma unroll
  for (int i = 0; i < 4; i++){
    int s = tid + 256*i;
    int jj = s >> 4, k4 = (s & 15)*4;
    f16x4 h;
    h[0]=(f16)t[k4][jj]; h[1]=(f16)t[k4+1][jj]; h[2]=(f16)t[k4+2][jj]; h[3]=(f16)t[k4+3][jj];
    *(f16x4*)&wT[((size_t)e*384 + proj*128 + j0 + jj)*C_ + k0 + k4] = h;
  }
}

__global__ __launch_bounds__(256) void conv_o(const float* __restrict__ op, f16* __restrict__ oT){
  int e = blockIdx.z;
  int n0 = blockIdx.x*64, k0 = blockIdx.y*64;
  __shared__ float t[64][65];
  int tid = threadIdx.x;
  #pragma unroll
  for (int i = 0; i < 4; i++){
    int s = tid + 256*i;
    int r = s >> 4, c4 = (s & 15)*4;   // r: k, c4: n
    f32x4 a = *(const f32x4*)&op[(size_t)e*H_*C_ + (size_t)(k0+r)*C_ + n0 + c4];
    t[r][c4]=a[0]; t[r][c4+1]=a[1]; t[r][c4+2]=a[2]; t[r][c4+3]=a[3];
  }
  __syncthreads();
  #pragma unroll
  for (int i = 0; i < 4; i++){
    int s = tid + 256*i;
    int nn = s >> 4, k4 = (s & 15)*4;
    f16x4 h;
    h[0]=(f16)t[k4][nn]; h[1]=(f16)t[k4+1][nn]; h[2]=(f16)t[k4+2][nn]; h[3]=(f16)t[k4+3][nn];
    *(f16x4*)&oT[((size_t)e*C_ + n0 + nn)*H_ + k0 + k4] = h;
  }
}

// ------------------------------------------------------------------
// gating v3: 32 tokens/block, 256 blocks (1/CU). Wave w = expert quad
// 4w..4w+3; lane = (token l&31, k-half l>>5). sim chunk staged in LDS,
// read as broadcast b128. f64 accumulation (2-way ILP), shuffle reduce,
// 32-lane-parallel epilogue.
// ------------------------------------------------------------------
__global__ __launch_bounds__(256) void gate_kernel(const float* __restrict__ x,
    const float* __restrict__ sim, const double* __restrict__ wninv,
    const double* __restrict__ sigg, int* __restrict__ cnt,
    int* __restrict__ list, float* __restrict__ listw){
  __shared__ __align__(16) float st[4096];   // sim chunk [256 k][16 e]
  __shared__ double dred[32][17];
  int tid = threadIdx.x;
  int eq = tid >> 6, l = tid & 63;
  int tok = l & 31, kh = l >> 5;
  int n0 = blockIdx.x * 32;
  const float* xr = x + (size_t)(n0 + tok) * C_;
  double accA[4] = {0,0,0,0}, accB[4] = {0,0,0,0};
  double ssqA = 0.0, ssqB = 0.0;
  for (int k0 = 0; k0 < C_; k0 += 256){
    __syncthreads();
    #pragma unroll
    for (int i = 0; i < 4; i++){
      int idx = tid + 256*i;
      *(f32x4*)&st[idx*4] = *(const f32x4*)&sim[(size_t)k0*E_ + idx*4];
    }
    __syncthreads();
    #pragma unroll
    for (int q = 0; q < 32; q++){
      int kl = kh*128 + q*4;
      f32x4 xv = *(const f32x4*)&xr[k0 + kl];
      #pragma unroll
      for (int j = 0; j < 4; j++){
        f32x4 sv = *(const f32x4*)&st[(kl+j)*E_ + eq*4];
        double xd = (double)xv[j];
        if (j & 1){
          accB[0] += xd*(double)sv[0]; accB[1] += xd*(double)sv[1];
          accB[2] += xd*(double)sv[2]; accB[3] += xd*(double)sv[3];
          if (eq == 0) ssqB += xd*xd;
        } else {
          accA[0] += xd*(double)sv[0]; accA[1] += xd*(double)sv[1];
          accA[2] += xd*(double)sv[2]; accA[3] += xd*(double)sv[3];
          if (eq == 0) ssqA += xd*xd;
        }
      }
    }
  }
  double acc[4];
  #pragma unroll
  for (int j = 0; j < 4; j++){
    acc[j] = accA[j] + accB[j];
    acc[j] += __shfl_xor(acc[j], 32);
  }
  double ssq = ssqA + ssqB;
  ssq += __shfl_xor(ssq, 32);
  if (l < 32){
    #pragma unroll
    for (int j = 0; j < 4; j++) dred[tok][eq*4 + j] = acc[j];
    if (eq == 0) dred[tok][16] = ssq;
  }
  __syncthreads();
  if (tid < 32){
    int n = n0 + tid;
    double inv = 1.0 / fmax(sqrt(dred[tid][16]), 1e-12);
    double logit[E_]; bool mask[E_]; int active = 0;
    #pragma unroll
    for (int e = 0; e < E_; e++){
      logit[e] = dred[tid][e] * inv * wninv[e] - sigg[e];
      mask[e] = logit[e] > 0.0;
      if (mask[e]) active++;
    }
    if (active == 0){
      int i1 = -1, i2 = -1; double b1 = -1e300, b2 = -1e300;
      for (int e = 0; e < E_; e++){
        double v = logit[e];
        if (v > b1){ b2 = b1; i2 = i1; b1 = v; i1 = e; }
        else if (v > b2){ b2 = v; i2 = e; }
      }
      mask[i1] = true; mask[i2] = true;
    }
    double mx = -1e300;
    for (int e = 0; e < E_; e++){ if (mask[e]) mx = fmax(mx, fmax(logit[e], 0.0)); }
    double ex[E_]; double sum = 0.0;
    for (int e = 0; e < E_; e++){
      double gval = fmax(logit[e], 0.0);
      ex[e] = mask[e] ? exp(gval - mx) : 0.0;
      sum += ex[e];
    }
    double isum = 1.0 / sum;
    for (int e = 0; e < E_; e++){
      if (mask[e]){
        int p = atomicAdd(&cnt[e], 1);
        list[e*N_TOK + p]  = n;
        listw[e*N_TOK + p] = (float)(ex[e]*isum);
      }
    }
  }
}

// ------------------------------------------------------------------
// tile list: for each expert, one entry per 64-token m-tile
// ------------------------------------------------------------------
__global__ __launch_bounds__(64) void tile_builder(const int* __restrict__ cnt,
    int* __restrict__ tlist, int* __restrict__ ntile){
  __shared__ int nts[E_];
  int tid = threadIdx.x;
  if (tid < E_) nts[tid] = (cnt[tid] + 63) >> 6;
  __syncthreads();
  if (tid < E_){
    int base = 0;
    for (int e = 0; e < tid; e++) base += nts[e];
    int nt = nts[tid];
    for (int t = 0; t < nt; t++) tlist[base + t] = (tid << 8) | t;
    if (tid == E_-1) *ntile = base + nt;
  }
}

// ------------------------------------------------------------------
// grouped QKV GEMM v2: tile-list driven, 64x128xBK128, f16x8 staging,
// 4 waves (wave-tile 32x64), weighted fp32 atomic scatter.
// ------------------------------------------------------------------
#define LDT 136
__global__ __launch_bounds__(256) void qkv_gemm(const f16* __restrict__ xh,
    const f16* __restrict__ wT, const int* __restrict__ cnt,
    const int* __restrict__ list, const float* __restrict__ listw,
    const int* __restrict__ tlist, const int* __restrict__ ntile,
    float* __restrict__ qkv){
  __shared__ __align__(16) f16 a_s[64*LDT];
  __shared__ __align__(16) f16 b_s[128*LDT];
  __shared__ int tok_s[64];
  __shared__ float wgt_s[64];
  int nitems = (*ntile) * 3;
  int tid = threadIdx.x;
  int l = tid & 63, wv = tid >> 6;
  int wm = wv >> 1, wn = wv & 1;
  int g = l >> 4, c = l & 15;
  for (int w = blockIdx.x; w < nitems; w += gridDim.x){
    int tile = w / 3, nb = w - tile*3;
    int ent = tlist[tile];
    int e = ent >> 8, mt = ent & 255;
    int ce = cnt[e];
    int m0 = mt * 64;
    if (tid < 64){
      int gr = m0 + tid;
      tok_s[tid] = (gr < ce) ? list[e*N_TOK + gr] : 0;
      wgt_s[tid] = (gr < ce) ? listw[e*N_TOK + gr] : 0.f;
    }
    __syncthreads();
    f32x4 acc[2][4];
    #pragma unroll
    for (int m = 0; m < 2; m++)
      #pragma unroll
      for (int n = 0; n < 4; n++) acc[m][n] = (f32x4){0.f,0.f,0.f,0.f};
    const f16* Bbase = wT + ((size_t)e*384 + nb*128)*C_;
    for (int k0 = 0; k0 < C_; k0 += 128){
      #pragma unroll
      for (int i = 0; i < 4; i++){
        int s = tid + 256*i;
        int r = s >> 4, cs = (s & 15)*8;
        f16x8 v = *(const f16x8*)&xh[(size_t)tok_s[r]*C_ + k0 + cs];
        *(f16x8*)&a_s[r*LDT + cs] = v;
      }
      #pragma unroll
      for (int i = 0; i < 8; i++){
        int s = tid + 256*i;
        int j = s >> 4, cs = (s & 15)*8;
        f16x8 v = *(const f16x8*)&Bbase[(size_t)j*C_ + k0 + cs];
        *(f16x8*)&b_s[j*LDT + cs] = v;
      }
      __syncthreads();
      #pragma unroll
      for (int ks = 0; ks < 4; ks++){
        f16x8 af[2], bf[4];
        #pragma unroll
        for (int m = 0; m < 2; m++)
          af[m] = *(const f16x8*)&a_s[(wm*32 + m*16 + c)*LDT + ks*32 + 8*g];
        #pragma unroll
        for (int n = 0; n < 4; n++)
          bf[n] = *(const f16x8*)&b_s[(wn*64 + n*16 + c)*LDT + ks*32 + 8*g];
        #pragma unroll
        for (int m = 0; m < 2; m++)
          #pragma unroll
          for (int n = 0; n < 4; n++)
            acc[m][n] = MFMA(af[m], bf[n], acc[m][n]);
      }
      __syncthreads();
    }
    #pragma unroll
    for (int m = 0; m < 2; m++){
      #pragma unroll
      for (int i = 0; i < 4; i++){
        int row = wm*32 + m*16 + 4*g + i;
        int gr = m0 + row;
        if (gr < ce){
          int tok = tok_s[row]; float wgt = wgt_s[row];
          #pragma unroll
          for (int n = 0; n < 4; n++){
            int col = nb*128 + wn*64 + n*16 + c;
            atomicAdd(&qkv[(size_t)tok*384 + col], wgt*acc[m][n][i]);
          }
        }
      }
    }
    __syncthreads();
  }
}

// ------------------------------------------------------------------
// RoPE on q,k halves of qkv buffer; emit fp16 q/k/v arrays
// ------------------------------------------------------------------
__global__ __launch_bounds__(192) void rope_kernel(const float* __restrict__ qkv,
    const int* __restrict__ pos_ids, f16* __restrict__ qh, f16* __restrict__ kh,
    f16* __restrict__ vh){
  int n = blockIdx.x; int tid = threadIdx.x;
  const float* row = qkv + (size_t)n * 384;
  if (tid < 128){
    int isK = tid >> 6, j = tid & 63;
    const float* src = row + isK*H_;
    float a = src[j], b = src[j+64];
    int pos = pos_ids[n & (T_-1)];
    float freq = exp2f(-(float)j * 0.20762050593046015f);
    float ang = (float)pos * freq;
    float s, cc;
    sincosf(ang, &s, &cc);
    f16* dst = isK ? kh : qh;
    dst[(size_t)n*H_ + j]      = (f16)(a*cc - b*s);
    dst[(size_t)n*H_ + j + 64] = (f16)(b*cc + a*s);
  } else {
    int j = (tid - 128)*2;
    vh[(size_t)n*H_ + j]     = (f16)row[256 + j];
    vh[(size_t)n*H_ + j + 1] = (f16)row[256 + j + 1];
  }
}

// ------------------------------------------------------------------
// flash attention, causal, D=128 (unchanged)
// ------------------------------------------------------------------
#define LDK_ 136
#define LDV_ 72
__global__ __launch_bounds__(128) void attn_kernel(const f16* __restrict__ qh,
    const f16* __restrict__ kh, const f16* __restrict__ vh, f16* __restrict__ ah){
  int bid = blockIdx.x;
  int b = bid >> 6, qt = bid & 63;
  int q0 = qt*32, nbase = b*T_;
  __shared__ __align__(16) f16 q_s[32*LDK_];
  __shared__ __align__(16) f16 k_s[64*LDK_];
  __shared__ __align__(16) f16 v_s[128*LDV_];
  __shared__ __align__(16) f16 p_s[2*16*LDV_];
  int tid = threadIdx.x;
  int l = tid & 63, w = tid >> 6;
  int g = l >> 4, c = l & 15;
  #pragma unroll
  for (int i = 0; i < 4; i++){
    int slot = tid + 128*i;
    int ch = slot & 15, r = slot >> 4;
    *(u32x4*)&q_s[r*LDK_ + ch*8] = *(const u32x4*)&qh[((size_t)(nbase + q0 + r))*H_ + ch*8];
  }
  f32x4 oacc[8];
  #pragma unroll
  for (int nb = 0; nb < 8; nb++) oacc[nb] = (f32x4){0,0,0,0};
  float m_run[4], l_run[4];
  #pragma unroll
  for (int i = 0; i < 4; i++){ m_run[i] = -1e30f; l_run[i] = 0.f; }
  int nk = (q0 + 31)/64 + 1;
  for (int kt = 0; kt < nk; kt++){
    int kb = kt*64;
    __syncthreads();
    #pragma unroll
    for (int i = 0; i < 8; i++){
      int slot = tid + 128*i;
      int ch = slot & 15, r = slot >> 4;
      *(u32x4*)&k_s[r*LDK_ + ch*8] = *(const u32x4*)&kh[((size_t)(nbase + kb + r))*H_ + ch*8];
    }
    #pragma unroll
    for (int i = 0; i < 8; i++){
      int slot = tid + 128*i;
      int tok = slot & 63, ch = slot >> 6;
      f16x8 raw = *(const f16x8*)&vh[((size_t)(nbase + kb + tok))*H_ + ch*8];
      #pragma unroll
      for (int j = 0; j < 8; j++) v_s[(ch*8 + j)*LDV_ + tok] = raw[j];
    }
    __syncthreads();
    f32x4 sacc[4];
    #pragma unroll
    for (int f = 0; f < 4; f++) sacc[f] = (f32x4){0,0,0,0};
    #pragma unroll
    for (int ks = 0; ks < 4; ks++){
      f16x8 qf = *(const f16x8*)&q_s[(w*16 + c)*LDK_ + ks*32 + 8*g];
      #pragma unroll
      for (int f = 0; f < 4; f++){
        f16x8 kf = *(const f16x8*)&k_s[(f*16 + c)*LDK_ + ks*32 + 8*g];
        sacc[f] = MFMA(qf, kf, sacc[f]);
      }
    }
    float tm[4];
    #pragma unroll
    for (int i = 0; i < 4; i++) tm[i] = -1e30f;
    #pragma unroll
    for (int f = 0; f < 4; f++){
      int kg = kb + f*16 + c;
      #pragma unroll
      for (int i = 0; i < 4; i++){
        int qg = q0 + w*16 + 4*g + i;
        float s = sacc[f][i] * SCALE_;
        if (kg > qg) s = -1e30f;
        sacc[f][i] = s;
        tm[i] = fmaxf(tm[i], s);
      }
    }
    #pragma unroll
    for (int i = 0; i < 4; i++){
      #pragma unroll
      for (int d = 1; d <= 8; d <<= 1) tm[i] = fmaxf(tm[i], __shfl_xor(tm[i], d));
      float mn = fmaxf(m_run[i], tm[i]);
      float al = __expf(m_run[i] - mn);
      m_run[i] = mn;
      l_run[i] *= al;
      #pragma unroll
      for (int nb = 0; nb < 8; nb++) oacc[nb][i] *= al;
    }
    float rs[4] = {0.f,0.f,0.f,0.f};
    #pragma unroll
    for (int f = 0; f < 4; f++){
      #pragma unroll
      for (int i = 0; i < 4; i++){
        float p = __expf(sacc[f][i] - m_run[i]);
        rs[i] += p;
        p_s[w*16*LDV_ + (4*g + i)*LDV_ + f*16 + c] = (f16)p;
      }
    }
    #pragma unroll
    for (int i = 0; i < 4; i++){
      #pragma unroll
      for (int d = 1; d <= 8; d <<= 1) rs[i] += __shfl_xor(rs[i], d);
      l_run[i] += rs[i];
    }
    #pragma unroll
    for (int ks = 0; ks < 2; ks++){
      f16x8 pf = *(const f16x8*)&p_s[w*16*LDV_ + c*LDV_ + ks*32 + 8*g];
      #pragma unroll
      for (int nb = 0; nb < 8; nb++){
        f16x8 vf = *(const f16x8*)&v_s[(c + 16*nb)*LDV_ + ks*32 + 8*g];
        oacc[nb] = MFMA(pf, vf, oacc[nb]);
      }
    }
  }
  #pragma unroll
  for (int i = 0; i < 4; i++){
    float inv = 1.f / l_run[i];
    int qg = q0 + w*16 + 4*g + i;
    #pragma unroll
    for (int nb = 0; nb < 8; nb++)
      ah[((size_t)(nbase + qg))*H_ + c + 16*nb] = (f16)(oacc[nb][i] * inv);
  }
}

// ------------------------------------------------------------------
// grouped O GEMM v2: tile-list driven, K=128 single stage,
// A pre-scaled by routing weight, atomic scatter into out.
// ------------------------------------------------------------------
__global__ __launch_bounds__(256) void o_gemm(const f16* __restrict__ ah,
    const f16* __restrict__ oT, const int* __restrict__ cnt,
    const int* __restrict__ list, const float* __restrict__ listw,
    const int* __restrict__ tlist, const int* __restrict__ ntile,
    float* __restrict__ out){
  __shared__ __align__(16) f16 a_s[64*LDT];
  __shared__ __align__(16) f16 b_s[128*LDT];
  __shared__ int tok_s[64];
  __shared__ float wgt_s[64];
  int nitems = (*ntile) * 16;
  int tid = threadIdx.x;
  int l = tid & 63, wv = tid >> 6;
  int wm = wv >> 1, wn = wv & 1;
  int g = l >> 4, c = l & 15;
  for (int w = blockIdx.x; w < nitems; w += gridDim.x){
    int tile = w >> 4, nbt = w & 15;
    int ent = tlist[tile];
    int e = ent >> 8, mt = ent & 255;
    int ce = cnt[e];
    int m0 = mt * 64, n0 = nbt * 128;
    if (tid < 64){
      int gr = m0 + tid;
      tok_s[tid] = (gr < ce) ? list[e*N_TOK + gr] : 0;
      wgt_s[tid] = (gr < ce) ? listw[e*N_TOK + gr] : 0.f;
    }
    __syncthreads();
    #pragma unroll
    for (int i = 0; i < 4; i++){
      int s = tid + 256*i;
      int r = s >> 4, cs = (s & 15)*8;
      f16x8 v = *(const f16x8*)&ah[(size_t)tok_s[r]*H_ + cs];
      float wgt = wgt_s[r];
      f16x8 o;
      #pragma unroll
      for (int j = 0; j < 8; j++) o[j] = (f16)((float)v[j]*wgt);
      *(f16x8*)&a_s[r*LDT + cs] = o;
    }
    #pragma unroll
    for (int i = 0; i < 8; i++){
      int s = tid + 256*i;
      int j = s >> 4, cs = (s & 15)*8;
      f16x8 v = *(const f16x8*)&oT[((size_t)e*C_ + n0 + j)*H_ + cs];
      *(f16x8*)&b_s[j*LDT + cs] = v;
    }
    __syncthreads();
    f32x4 acc[2][4];
    #pragma unroll
    for (int m = 0; m < 2; m++)
      #pragma unroll
      for (int n = 0; n < 4; n++) acc[m][n] = (f32x4){0.f,0.f,0.f,0.f};
    #pragma unroll
    for (int ks = 0; ks < 4; ks++){
      f16x8 af[2], bf[4];
      #pragma unroll
      for (int m = 0; m < 2; m++)
        af[m] = *(const f16x8*)&a_s[(wm*32 + m*16 + c)*LDT + ks*32 + 8*g];
      #pragma unroll
      for (int n = 0; n < 4; n++)
        bf[n] = *(const f16x8*)&b_s[(wn*64 + n*16 + c)*LDT + ks*32 + 8*g];
      #pragma unroll
      for (int m = 0; m < 2; m++)
        #pragma unroll
        for (int n = 0; n < 4; n++)
          acc[m][n] = MFMA(af[m], bf[n], acc[m][n]);
    }
    #pragma unroll
    for (int m = 0; m < 2; m++){
      #pragma unroll
      for (int i = 0; i < 4; i++){
        int row = wm*32 + m*16 + 4*g + i;
        int gr = m0 + row;
        if (gr < ce){
          int tok = tok_s[row];
          #pragma unroll
          for (int n = 0; n < 4; n++){
            int col = n0 + wn*64 + n*16 + c;
            atomicAdd(&out[(size_t)tok*C_ + col], acc[m][n][i]);
          }
        }
      }
    }
    __syncthreads();
  }
}

// ------------------------------------------------------------------
extern "C" void kernel_launch(void* const* d_in, const int* in_sizes, int n_in,
                              void* d_out, int out_size, void* d_ws, size_t ws_size,
                              hipStream_t stream){
  const float* hs    = (const float*)d_in[0];
  const int*   pos   = (const int*)d_in[1];
  const float* sim   = (const float*)d_in[2];
  const float* gates = (const float*)d_in[3];
  const float* qp    = (const float*)d_in[4];
  const float* kp    = (const float*)d_in[5];
  const float* vp    = (const float*)d_in[6];
  const float* op    = (const float*)d_in[7];
  float* out = (float*)d_out;
  char* ws = (char*)d_ws;
  // workspace layout
  int*    cnt   = (int*)(ws + 0);               // 16 int
  int*    ntile = (int*)(ws + 64);              // 1 int
  double* wninv = (double*)(ws + 128);          // 16 f64
  double* sigg  = (double*)(ws + 256);          // 16 f64
  int*    tlist = (int*)(ws + 512);             // 2048 int
  int*    list  = (int*)(ws + 8704);            // 16*8192 int
  float*  listw = (float*)(ws + 532992);        // 16*8192 f32
  f16*    xh    = (f16*)(ws + 1057280);         // [8192][2048]
  f16*    wT    = (f16*)(ws + 34611712);        // [16][384][2048]
  f16*    oT    = (f16*)(ws + 59777536);        // [16][2048][128]
  float*  qkv   = (float*)(ws + 68166144);      // [8192][384] f32
  f16*    qh    = (f16*)(ws + 80749056);        // [8192][128]
  f16*    kh    = (f16*)(ws + 82846208);
  f16*    vh    = (f16*)(ws + 84943360);
  f16*    ah    = (f16*)(ws + 87040512);        // ends 89137664

  hipMemsetAsync(cnt, 0, 64, stream);
  hipMemsetAsync(qkv, 0, (size_t)N_TOK*384*4, stream);
  hipMemsetAsync(out, 0, (size_t)N_TOK*C_*4, stream);

  prep_kernel<<<1, 256, 0, stream>>>(sim, gates, wninv, sigg);
  conv_x<<<4096, 256, 0, stream>>>(hs, xh);
  conv_w<<<dim3(32, 2, 48), 256, 0, stream>>>(qp, kp, vp, wT);
  conv_o<<<dim3(32, 2, 16), 256, 0, stream>>>(op, oT);
  gate_kernel<<<256, 256, 0, stream>>>(hs, sim, wninv, sigg, cnt, list, listw);
  tile_builder<<<1, 64, 0, stream>>>(cnt, tlist, ntile);
  qkv_gemm<<<1024, 256, 0, stream>>>(xh, wT, cnt, list, listw, tlist, ntile, qkv);
  rope_kernel<<<N_TOK, 192, 0, stream>>>(qkv, pos, qh, kh, vh);
  attn_kernel<<<256, 128, 0, stream>>>(qh, kh, vh, ah);
  o_gemm<<<2048, 256, 0, stream>>>(ah, oT, cnt, list, listw, tlist, ntile, out);
}

// Round 5
// 622.042 us; speedup vs baseline: 2.7279x; 1.1457x over previous
//
#include <hip/hip_runtime.h>
#include <hip/hip_fp16.h>

#define T_ 2048
#define C_ 2048
#define H_ 128
#define E_ 16
#define N_TOK 8192
#define SCALE_ 0.08838834764831845f   // 1/sqrt(128)

typedef _Float16 f16;
typedef _Float16 f16x4 __attribute__((ext_vector_type(4)));
typedef _Float16 f16x8 __attribute__((ext_vector_type(8)));
typedef float f32x4 __attribute__((ext_vector_type(4)));
typedef unsigned int u32x4 __attribute__((ext_vector_type(4)));

#define MFMA(a,b,c) __builtin_amdgcn_mfma_f32_16x16x32_f16(a,b,c,0,0,0)

__device__ __forceinline__ void gload16(const void* g, void* l){
  __builtin_amdgcn_global_load_lds(
      (const __attribute__((address_space(1))) unsigned int*)g,
      (__attribute__((address_space(3))) unsigned int*)l, 16, 0, 0);
}

// ------------------------------------------------------------------
// prep: column norms of sim_matrix (inverse, f64), sigmoid(gates)
// ------------------------------------------------------------------
__global__ __launch_bounds__(256) void prep_kernel(const float* __restrict__ sim,
    const float* __restrict__ gates, double* __restrict__ wninv, double* __restrict__ sigg){
  __shared__ double part[16][17];
  int tid = threadIdx.x;
  int col = tid & 15, grp = tid >> 4;
  double ssq = 0.0;
  for (int r = grp; r < C_; r += 16){ float v = sim[r*E_ + col]; ssq += (double)v*(double)v; }
  part[grp][col] = ssq;
  __syncthreads();
  if (tid < E_){
    double s = 0.0;
    #pragma unroll
    for (int g2 = 0; g2 < 16; g2++) s += part[g2][tid];
    wninv[tid] = 1.0 / fmax(sqrt(s), 1e-12);
    sigg[tid]  = 1.0 / (1.0 + exp(-(double)gates[tid]));
  }
}

// ------------------------------------------------------------------
// converts: x -> f16; q/k/v_proj -> f16 transposed [e][384][2048];
// o_proj -> f16 transposed [e][2048][128]
// ------------------------------------------------------------------
__global__ __launch_bounds__(256) void conv_x(const float* __restrict__ x, f16* __restrict__ xh){
  for (int v = blockIdx.x*256 + threadIdx.x; v < N_TOK*C_/4; v += 4096*256){
    f32x4 a = *(const f32x4*)&x[(size_t)v*4];
    f16x4 h; h[0]=(f16)a[0]; h[1]=(f16)a[1]; h[2]=(f16)a[2]; h[3]=(f16)a[3];
    *(f16x4*)&xh[(size_t)v*4] = h;
  }
}

__global__ __launch_bounds__(256) void conv_w(const float* __restrict__ qp,
    const float* __restrict__ kp, const float* __restrict__ vp, f16* __restrict__ wT){
  int ep = blockIdx.z; int e = ep/3, proj = ep - 3*e;
  const float* W = (proj==0?qp:(proj==1?kp:vp)) + (size_t)e*C_*H_;
  int k0 = blockIdx.x*64, j0 = blockIdx.y*64;
  __shared__ float t[64][65];
  int tid = threadIdx.x;
  #pragma unroll
  for (int i = 0; i < 4; i++){
    int s = tid + 256*i;
    int r = s >> 4, c4 = (s & 15)*4;
    f32x4 a = *(const f32x4*)&W[(size_t)(k0+r)*H_ + j0 + c4];
    t[r][c4]=a[0]; t[r][c4+1]=a[1]; t[r][c4+2]=a[2]; t[r][c4+3]=a[3];
  }
  __syncthreads();
  #pragma unroll
  for (int i = 0; i < 4; i++){
    int s = tid + 256*i;
    int jj = s >> 4, k4 = (s & 15)*4;
    f16x4 h;
    h[0]=(f16)t[k4][jj]; h[1]=(f16)t[k4+1][jj]; h[2]=(f16)t[k4+2][jj]; h[3]=(f16)t[k4+3][jj];
    *(f16x4*)&wT[((size_t)e*384 + proj*128 + j0 + jj)*C_ + k0 + k4] = h;
  }
}

__global__ __launch_bounds__(256) void conv_o(const float* __restrict__ op, f16* __restrict__ oT){
  int e = blockIdx.z;
  int n0 = blockIdx.x*64, k0 = blockIdx.y*64;
  __shared__ float t[64][65];
  int tid = threadIdx.x;
  #pragma unroll
  for (int i = 0; i < 4; i++){
    int s = tid + 256*i;
    int r = s >> 4, c4 = (s & 15)*4;   // r: k, c4: n
    f32x4 a = *(const f32x4*)&op[(size_t)e*H_*C_ + (size_t)(k0+r)*C_ + n0 + c4];
    t[r][c4]=a[0]; t[r][c4+1]=a[1]; t[r][c4+2]=a[2]; t[r][c4+3]=a[3];
  }
  __syncthreads();
  #pragma unroll
  for (int i = 0; i < 4; i++){
    int s = tid + 256*i;
    int nn = s >> 4, k4 = (s & 15)*4;
    f16x4 h;
    h[0]=(f16)t[k4][nn]; h[1]=(f16)t[k4+1][nn]; h[2]=(f16)t[k4+2][nn]; h[3]=(f16)t[k4+3][nn];
    *(f16x4*)&oT[((size_t)e*C_ + n0 + nn)*H_ + k0 + k4] = h;
  }
}

// ------------------------------------------------------------------
// gating v3 (unchanged): 32 tokens/block, f64 accumulation
// ------------------------------------------------------------------
__global__ __launch_bounds__(256) void gate_kernel(const float* __restrict__ x,
    const float* __restrict__ sim, const double* __restrict__ wninv,
    const double* __restrict__ sigg, int* __restrict__ cnt,
    int* __restrict__ list, float* __restrict__ listw){
  __shared__ __align__(16) float st[4096];   // sim chunk [256 k][16 e]
  __shared__ double dred[32][17];
  int tid = threadIdx.x;
  int eq = tid >> 6, l = tid & 63;
  int tok = l & 31, kh = l >> 5;
  int n0 = blockIdx.x * 32;
  const float* xr = x + (size_t)(n0 + tok) * C_;
  double accA[4] = {0,0,0,0}, accB[4] = {0,0,0,0};
  double ssqA = 0.0, ssqB = 0.0;
  for (int k0 = 0; k0 < C_; k0 += 256){
    __syncthreads();
    #pragma unroll
    for (int i = 0; i < 4; i++){
      int idx = tid + 256*i;
      *(f32x4*)&st[idx*4] = *(const f32x4*)&sim[(size_t)k0*E_ + idx*4];
    }
    __syncthreads();
    #pragma unroll
    for (int q = 0; q < 32; q++){
      int kl = kh*128 + q*4;
      f32x4 xv = *(const f32x4*)&xr[k0 + kl];
      #pragma unroll
      for (int j = 0; j < 4; j++){
        f32x4 sv = *(const f32x4*)&st[(kl+j)*E_ + eq*4];
        double xd = (double)xv[j];
        if (j & 1){
          accB[0] += xd*(double)sv[0]; accB[1] += xd*(double)sv[1];
          accB[2] += xd*(double)sv[2]; accB[3] += xd*(double)sv[3];
          if (eq == 0) ssqB += xd*xd;
        } else {
          accA[0] += xd*(double)sv[0]; accA[1] += xd*(double)sv[1];
          accA[2] += xd*(double)sv[2]; accA[3] += xd*(double)sv[3];
          if (eq == 0) ssqA += xd*xd;
        }
      }
    }
  }
  double acc[4];
  #pragma unroll
  for (int j = 0; j < 4; j++){
    acc[j] = accA[j] + accB[j];
    acc[j] += __shfl_xor(acc[j], 32);
  }
  double ssq = ssqA + ssqB;
  ssq += __shfl_xor(ssq, 32);
  if (l < 32){
    #pragma unroll
    for (int j = 0; j < 4; j++) dred[tok][eq*4 + j] = acc[j];
    if (eq == 0) dred[tok][16] = ssq;
  }
  __syncthreads();
  if (tid < 32){
    int n = n0 + tid;
    double inv = 1.0 / fmax(sqrt(dred[tid][16]), 1e-12);
    double logit[E_]; bool mask[E_]; int active = 0;
    #pragma unroll
    for (int e = 0; e < E_; e++){
      logit[e] = dred[tid][e] * inv * wninv[e] - sigg[e];
      mask[e] = logit[e] > 0.0;
      if (mask[e]) active++;
    }
    if (active == 0){
      int i1 = -1, i2 = -1; double b1 = -1e300, b2 = -1e300;
      for (int e = 0; e < E_; e++){
        double v = logit[e];
        if (v > b1){ b2 = b1; i2 = i1; b1 = v; i1 = e; }
        else if (v > b2){ b2 = v; i2 = e; }
      }
      mask[i1] = true; mask[i2] = true;
    }
    double mx = -1e300;
    for (int e = 0; e < E_; e++){ if (mask[e]) mx = fmax(mx, fmax(logit[e], 0.0)); }
    double ex[E_]; double sum = 0.0;
    for (int e = 0; e < E_; e++){
      double gval = fmax(logit[e], 0.0);
      ex[e] = mask[e] ? exp(gval - mx) : 0.0;
      sum += ex[e];
    }
    double isum = 1.0 / sum;
    for (int e = 0; e < E_; e++){
      if (mask[e]){
        int p = atomicAdd(&cnt[e], 1);
        list[e*N_TOK + p]  = n;
        listw[e*N_TOK + p] = (float)(ex[e]*isum);
      }
    }
  }
}

// ------------------------------------------------------------------
// tile lists: 64-gran (o_gemm) and 128-gran (qkv_gemm)
// ------------------------------------------------------------------
__global__ __launch_bounds__(64) void tile_builder(const int* __restrict__ cnt,
    int* __restrict__ tlist, int* __restrict__ ntile,
    int* __restrict__ tlist2, int* __restrict__ ntile2){
  __shared__ int nts[E_], nts2[E_];
  int tid = threadIdx.x;
  if (tid < E_){
    nts[tid]  = (cnt[tid] + 63) >> 6;
    nts2[tid] = (cnt[tid] + 127) >> 7;
  }
  __syncthreads();
  if (tid < E_){
    int base = 0, b2 = 0;
    for (int e = 0; e < tid; e++){ base += nts[e]; b2 += nts2[e]; }
    for (int t = 0; t < nts[tid];  t++) tlist[base + t] = (tid << 8) | t;
    for (int t = 0; t < nts2[tid]; t++) tlist2[b2 + t]  = (tid << 8) | t;
    if (tid == E_-1){ *ntile = base + nts[tid]; *ntile2 = b2 + nts2[tid]; }
  }
}

// ------------------------------------------------------------------
// grouped QKV GEMM v3 (m97 structure): 128x128 tile, BK=64, 4 waves
// (64x64 each), global_load_lds width-16 into linear LDS, double-
// buffered 2-phase (stage-next before compute, one barrier/K-step),
// weighted fp32 atomic scatter epilogue.
// ------------------------------------------------------------------
__global__ __launch_bounds__(256, 2) void qkv_gemm(const f16* __restrict__ xh,
    const f16* __restrict__ wT, const int* __restrict__ cnt,
    const int* __restrict__ list, const float* __restrict__ listw,
    const int* __restrict__ tlist2, const int* __restrict__ ntile2,
    float* __restrict__ qkv){
  __shared__ __align__(16) f16 a_s[2][128][64];
  __shared__ __align__(16) f16 b_s[2][128][64];
  __shared__ int tok_s[128];
  __shared__ float wgt_s[128];
  int nitems = (*ntile2) * 3;
  int tid = threadIdx.x;
  int l = tid & 63, wv = tid >> 6;
  int wm = wv >> 1, wn = wv & 1;
  int g = l >> 4, c = l & 15;
  for (int w = blockIdx.x; w < nitems; w += gridDim.x){
    int tile = w / 3, nb = w - tile*3;
    int ent = tlist2[tile];
    int e = ent >> 8, mt = ent & 255;
    int ce = cnt[e];
    int m0 = mt * 128;
    if (tid < 128){
      int gr = m0 + tid;
      tok_s[tid] = (gr < ce) ? list[e*N_TOK + gr] : 0;
      wgt_s[tid] = (gr < ce) ? listw[e*N_TOK + gr] : 0.f;
    }
    __syncthreads();
    // per-thread staging descriptors: ids tid+256*i, row=id>>3, ch=id&7
    const f16* Bbase = wT + ((size_t)e*384 + nb*128)*C_;
    const f16* agp[4]; const f16* bgp[4];
    #pragma unroll
    for (int i = 0; i < 4; i++){
      int id = tid + 256*i;
      int row = id >> 3, ch = id & 7;
      agp[i] = xh + (size_t)tok_s[row]*C_ + ch*8;
      bgp[i] = Bbase + (size_t)row*C_ + ch*8;
    }
    f32x4 acc[4][4];
    #pragma unroll
    for (int m = 0; m < 4; m++)
      #pragma unroll
      for (int n = 0; n < 4; n++) acc[m][n] = (f32x4){0.f,0.f,0.f,0.f};
    // prologue: stage buf0 @k0=0
    #pragma unroll
    for (int i = 0; i < 4; i++){
      int id = tid + 256*i;
      gload16(agp[i], &a_s[0][0][0] + (size_t)id*8);
      gload16(bgp[i], &b_s[0][0][0] + (size_t)id*8);
    }
    __syncthreads();   // drains vmcnt
    int cur = 0;
    for (int k0 = 0; k0 < C_; k0 += 64){
      int nxt = k0 + 64;
      if (nxt < C_){
        int nb2 = cur ^ 1;
        #pragma unroll
        for (int i = 0; i < 4; i++){
          int id = tid + 256*i;
          gload16(agp[i] + nxt, &a_s[nb2][0][0] + (size_t)id*8);
          gload16(bgp[i] + nxt, &b_s[nb2][0][0] + (size_t)id*8);
        }
      }
      #pragma unroll
      for (int ks = 0; ks < 2; ks++){
        f16x8 af[4], bf[4];
        #pragma unroll
        for (int m = 0; m < 4; m++)
          af[m] = *(const f16x8*)&a_s[cur][wm*64 + m*16 + c][ks*32 + 8*g];
        #pragma unroll
        for (int n = 0; n < 4; n++)
          bf[n] = *(const f16x8*)&b_s[cur][wn*64 + n*16 + c][ks*32 + 8*g];
        #pragma unroll
        for (int m = 0; m < 4; m++)
          #pragma unroll
          for (int n = 0; n < 4; n++)
            acc[m][n] = MFMA(af[m], bf[n], acc[m][n]);
      }
      __syncthreads();   // drains next-tile vmcnt; all waves done reading cur
      cur ^= 1;
    }
    #pragma unroll
    for (int m = 0; m < 4; m++){
      #pragma unroll
      for (int i = 0; i < 4; i++){
        int row = wm*64 + m*16 + 4*g + i;
        int gr = m0 + row;
        if (gr < ce){
          int tok = tok_s[row]; float wgt = wgt_s[row];
          #pragma unroll
          for (int n = 0; n < 4; n++){
            int col = nb*128 + wn*64 + n*16 + c;
            atomicAdd(&qkv[(size_t)tok*384 + col], wgt*acc[m][n][i]);
          }
        }
      }
    }
    __syncthreads();   // protect tok_s/LDS for next item
  }
}

// ------------------------------------------------------------------
// RoPE on q,k halves of qkv buffer; emit fp16 q/k/v arrays
// ------------------------------------------------------------------
__global__ __launch_bounds__(192) void rope_kernel(const float* __restrict__ qkv,
    const int* __restrict__ pos_ids, f16* __restrict__ qh, f16* __restrict__ kh,
    f16* __restrict__ vh){
  int n = blockIdx.x; int tid = threadIdx.x;
  const float* row = qkv + (size_t)n * 384;
  if (tid < 128){
    int isK = tid >> 6, j = tid & 63;
    const float* src = row + isK*H_;
    float a = src[j], b = src[j+64];
    int pos = pos_ids[n & (T_-1)];
    float freq = exp2f(-(float)j * 0.20762050593046015f);
    float ang = (float)pos * freq;
    float s, cc;
    sincosf(ang, &s, &cc);
    f16* dst = isK ? kh : qh;
    dst[(size_t)n*H_ + j]      = (f16)(a*cc - b*s);
    dst[(size_t)n*H_ + j + 64] = (f16)(b*cc + a*s);
  } else {
    int j = (tid - 128)*2;
    vh[(size_t)n*H_ + j]     = (f16)row[256 + j];
    vh[(size_t)n*H_ + j + 1] = (f16)row[256 + j + 1];
  }
}

// ------------------------------------------------------------------
// flash attention, causal, D=128 (unchanged)
// ------------------------------------------------------------------
#define LDK_ 136
#define LDV_ 72
__global__ __launch_bounds__(128) void attn_kernel(const f16* __restrict__ qh,
    const f16* __restrict__ kh, const f16* __restrict__ vh, f16* __restrict__ ah){
  int bid = blockIdx.x;
  int b = bid >> 6, qt = bid & 63;
  int q0 = qt*32, nbase = b*T_;
  __shared__ __align__(16) f16 q_s[32*LDK_];
  __shared__ __align__(16) f16 k_s[64*LDK_];
  __shared__ __align__(16) f16 v_s[128*LDV_];
  __shared__ __align__(16) f16 p_s[2*16*LDV_];
  int tid = threadIdx.x;
  int l = tid & 63, w = tid >> 6;
  int g = l >> 4, c = l & 15;
  #pragma unroll
  for (int i = 0; i < 4; i++){
    int slot = tid + 128*i;
    int ch = slot & 15, r = slot >> 4;
    *(u32x4*)&q_s[r*LDK_ + ch*8] = *(const u32x4*)&qh[((size_t)(nbase + q0 + r))*H_ + ch*8];
  }
  f32x4 oacc[8];
  #pragma unroll
  for (int nb = 0; nb < 8; nb++) oacc[nb] = (f32x4){0,0,0,0};
  float m_run[4], l_run[4];
  #pragma unroll
  for (int i = 0; i < 4; i++){ m_run[i] = -1e30f; l_run[i] = 0.f; }
  int nk = (q0 + 31)/64 + 1;
  for (int kt = 0; kt < nk; kt++){
    int kb = kt*64;
    __syncthreads();
    #pragma unroll
    for (int i = 0; i < 8; i++){
      int slot = tid + 128*i;
      int ch = slot & 15, r = slot >> 4;
      *(u32x4*)&k_s[r*LDK_ + ch*8] = *(const u32x4*)&kh[((size_t)(nbase + kb + r))*H_ + ch*8];
    }
    #pragma unroll
    for (int i = 0; i < 8; i++){
      int slot = tid + 128*i;
      int tok = slot & 63, ch = slot >> 6;
      f16x8 raw = *(const f16x8*)&vh[((size_t)(nbase + kb + tok))*H_ + ch*8];
      #pragma unroll
      for (int j = 0; j < 8; j++) v_s[(ch*8 + j)*LDV_ + tok] = raw[j];
    }
    __syncthreads();
    f32x4 sacc[4];
    #pragma unroll
    for (int f = 0; f < 4; f++) sacc[f] = (f32x4){0,0,0,0};
    #pragma unroll
    for (int ks = 0; ks < 4; ks++){
      f16x8 qf = *(const f16x8*)&q_s[(w*16 + c)*LDK_ + ks*32 + 8*g];
      #pragma unroll
      for (int f = 0; f < 4; f++){
        f16x8 kf = *(const f16x8*)&k_s[(f*16 + c)*LDK_ + ks*32 + 8*g];
        sacc[f] = MFMA(qf, kf, sacc[f]);
      }
    }
    float tm[4];
    #pragma unroll
    for (int i = 0; i < 4; i++) tm[i] = -1e30f;
    #pragma unroll
    for (int f = 0; f < 4; f++){
      int kg = kb + f*16 + c;
      #pragma unroll
      for (int i = 0; i < 4; i++){
        int qg = q0 + w*16 + 4*g + i;
        float s = sacc[f][i] * SCALE_;
        if (kg > qg) s = -1e30f;
        sacc[f][i] = s;
        tm[i] = fmaxf(tm[i], s);
      }
    }
    #pragma unroll
    for (int i = 0; i < 4; i++){
      #pragma unroll
      for (int d = 1; d <= 8; d <<= 1) tm[i] = fmaxf(tm[i], __shfl_xor(tm[i], d));
      float mn = fmaxf(m_run[i], tm[i]);
      float al = __expf(m_run[i] - mn);
      m_run[i] = mn;
      l_run[i] *= al;
      #pragma unroll
      for (int nb = 0; nb < 8; nb++) oacc[nb][i] *= al;
    }
    float rs[4] = {0.f,0.f,0.f,0.f};
    #pragma unroll
    for (int f = 0; f < 4; f++){
      #pragma unroll
      for (int i = 0; i < 4; i++){
        float p = __expf(sacc[f][i] - m_run[i]);
        rs[i] += p;
        p_s[w*16*LDV_ + (4*g + i)*LDV_ + f*16 + c] = (f16)p;
      }
    }
    #pragma unroll
    for (int i = 0; i < 4; i++){
      #pragma unroll
      for (int d = 1; d <= 8; d <<= 1) rs[i] += __shfl_xor(rs[i], d);
      l_run[i] += rs[i];
    }
    #pragma unroll
    for (int ks = 0; ks < 2; ks++){
      f16x8 pf = *(const f16x8*)&p_s[w*16*LDV_ + c*LDV_ + ks*32 + 8*g];
      #pragma unroll
      for (int nb = 0; nb < 8; nb++){
        f16x8 vf = *(const f16x8*)&v_s[(c + 16*nb)*LDV_ + ks*32 + 8*g];
        oacc[nb] = MFMA(pf, vf, oacc[nb]);
      }
    }
  }
  #pragma unroll
  for (int i = 0; i < 4; i++){
    float inv = 1.f / l_run[i];
    int qg = q0 + w*16 + 4*g + i;
    #pragma unroll
    for (int nb = 0; nb < 8; nb++)
      ah[((size_t)(nbase + qg))*H_ + c + 16*nb] = (f16)(oacc[nb][i] * inv);
  }
}

// ------------------------------------------------------------------
// grouped O GEMM v2 (unchanged): tile-list driven, K=128 single stage
// ------------------------------------------------------------------
#define LDT 136
__global__ __launch_bounds__(256) void o_gemm(const f16* __restrict__ ah,
    const f16* __restrict__ oT, const int* __restrict__ cnt,
    const int* __restrict__ list, const float* __restrict__ listw,
    const int* __restrict__ tlist, const int* __restrict__ ntile,
    float* __restrict__ out){
  __shared__ __align__(16) f16 a_s[64*LDT];
  __shared__ __align__(16) f16 b_s[128*LDT];
  __shared__ int tok_s[64];
  __shared__ float wgt_s[64];
  int nitems = (*ntile) * 16;
  int tid = threadIdx.x;
  int l = tid & 63, wv = tid >> 6;
  int wm = wv >> 1, wn = wv & 1;
  int g = l >> 4, c = l & 15;
  for (int w = blockIdx.x; w < nitems; w += gridDim.x){
    int tile = w >> 4, nbt = w & 15;
    int ent = tlist[tile];
    int e = ent >> 8, mt = ent & 255;
    int ce = cnt[e];
    int m0 = mt * 64, n0 = nbt * 128;
    if (tid < 64){
      int gr = m0 + tid;
      tok_s[tid] = (gr < ce) ? list[e*N_TOK + gr] : 0;
      wgt_s[tid] = (gr < ce) ? listw[e*N_TOK + gr] : 0.f;
    }
    __syncthreads();
    #pragma unroll
    for (int i = 0; i < 4; i++){
      int s = tid + 256*i;
      int r = s >> 4, cs = (s & 15)*8;
      f16x8 v = *(const f16x8*)&ah[(size_t)tok_s[r]*H_ + cs];
      float wgt = wgt_s[r];
      f16x8 o;
      #pragma unroll
      for (int j = 0; j < 8; j++) o[j] = (f16)((float)v[j]*wgt);
      *(f16x8*)&a_s[r*LDT + cs] = o;
    }
    #pragma unroll
    for (int i = 0; i < 8; i++){
      int s = tid + 256*i;
      int j = s >> 4, cs = (s & 15)*8;
      f16x8 v = *(const f16x8*)&oT[((size_t)e*C_ + n0 + j)*H_ + cs];
      *(f16x8*)&b_s[j*LDT + cs] = v;
    }
    __syncthreads();
    f32x4 acc[2][4];
    #pragma unroll
    for (int m = 0; m < 2; m++)
      #pragma unroll
      for (int n = 0; n < 4; n++) acc[m][n] = (f32x4){0.f,0.f,0.f,0.f};
    #pragma unroll
    for (int ks = 0; ks < 4; ks++){
      f16x8 af[2], bf[4];
      #pragma unroll
      for (int m = 0; m < 2; m++)
        af[m] = *(const f16x8*)&a_s[(wm*32 + m*16 + c)*LDT + ks*32 + 8*g];
      #pragma unroll
      for (int n = 0; n < 4; n++)
        bf[n] = *(const f16x8*)&b_s[(wn*64 + n*16 + c)*LDT + ks*32 + 8*g];
      #pragma unroll
      for (int m = 0; m < 2; m++)
        #pragma unroll
        for (int n = 0; n < 4; n++)
          acc[m][n] = MFMA(af[m], bf[n], acc[m][n]);
    }
    #pragma unroll
    for (int m = 0; m < 2; m++){
      #pragma unroll
      for (int i = 0; i < 4; i++){
        int row = wm*32 + m*16 + 4*g + i;
        int gr = m0 + row;
        if (gr < ce){
          int tok = tok_s[row];
          #pragma unroll
          for (int n = 0; n < 4; n++){
            int col = n0 + wn*64 + n*16 + c;
            atomicAdd(&out[(size_t)tok*C_ + col], acc[m][n][i]);
          }
        }
      }
    }
    __syncthreads();
  }
}

// ------------------------------------------------------------------
extern "C" void kernel_launch(void* const* d_in, const int* in_sizes, int n_in,
                              void* d_out, int out_size, void* d_ws, size_t ws_size,
                              hipStream_t stream){
  const float* hs    = (const float*)d_in[0];
  const int*   pos   = (const int*)d_in[1];
  const float* sim   = (const float*)d_in[2];
  const float* gates = (const float*)d_in[3];
  const float* qp    = (const float*)d_in[4];
  const float* kp    = (const float*)d_in[5];
  const float* vp    = (const float*)d_in[6];
  const float* op    = (const float*)d_in[7];
  float* out = (float*)d_out;
  char* ws = (char*)d_ws;
  // workspace layout (same extent as round 4: ends 89137664)
  int*    cnt    = (int*)(ws + 0);               // 16 int
  int*    ntile  = (int*)(ws + 64);              // 1 int
  double* wninv  = (double*)(ws + 128);          // 16 f64
  double* sigg   = (double*)(ws + 256);          // 16 f64
  int*    tlist  = (int*)(ws + 512);             // 2048 int (64-gran)
  int*    list   = (int*)(ws + 8704);            // 16*8192 int
  float*  listw  = (float*)(ws + 532992);        // 16*8192 f32
  f16*    xh     = (f16*)(ws + 1057280);         // [8192][2048]
  f16*    wT     = (f16*)(ws + 34611712);        // [16][384][2048]
  f16*    oT     = (f16*)(ws + 59777536);        // [16][2048][128]
  float*  qkv    = (float*)(ws + 68166144);      // [8192][384] f32
  f16*    ah     = (f16*)(ws + 68166144);        // overlays qkv (dead after rope)
  f16*    qh     = (f16*)(ws + 80749056);        // [8192][128]
  f16*    kh     = (f16*)(ws + 82846208);
  f16*    vh     = (f16*)(ws + 84943360);
  int*    tlist2 = (int*)(ws + 87040512);        // 1024 int (128-gran)
  int*    ntile2 = (int*)(ws + 87044608);        // 1 int

  hipMemsetAsync(cnt, 0, 64, stream);
  hipMemsetAsync(qkv, 0, (size_t)N_TOK*384*4, stream);
  hipMemsetAsync(out, 0, (size_t)N_TOK*C_*4, stream);

  prep_kernel<<<1, 256, 0, stream>>>(sim, gates, wninv, sigg);
  conv_x<<<4096, 256, 0, stream>>>(hs, xh);
  conv_w<<<dim3(32, 2, 48), 256, 0, stream>>>(qp, kp, vp, wT);
  conv_o<<<dim3(32, 2, 16), 256, 0, stream>>>(op, oT);
  gate_kernel<<<256, 256, 0, stream>>>(hs, sim, wninv, sigg, cnt, list, listw);
  tile_builder<<<1, 64, 0, stream>>>(cnt, tlist, ntile, tlist2, ntile2);
  qkv_gemm<<<512, 256, 0, stream>>>(xh, wT, cnt, list, listw, tlist2, ntile2, qkv);
  rope_kernel<<<N_TOK, 192, 0, stream>>>(qkv, pos, qh, kh, vh);
  attn_kernel<<<256, 128, 0, stream>>>(qh, kh, vh, ah);
  o_gemm<<<2048, 256, 0, stream>>>(ah, oT, cnt, list, listw, tlist, ntile, out);
}